// Round 4
// baseline (2179.772 us; speedup 1.0000x reference)
//
#include <hip/hip_runtime.h>

// Problem constants (B=8, C=32, H=192, W=320)
#define IMH 192
#define IMW 320
#define HW_ (IMH * IMW)      // 61440
#define BB 8
#define FC 32
#define GR 8                 // gather radius: covers |disp| < 8 (~4 sigma)
#define CCH 224              // concat channels/px: [p0 feat 64][corr 96][p1 feat 64]

typedef unsigned short ushortT;
typedef __attribute__((ext_vector_type(8))) short short8;   // 8 bf16 = 4 VGPRs
typedef __attribute__((ext_vector_type(4))) float f32x4;

union FragU { uint4 u; short8 s8; };

__device__ __forceinline__ ushortT f2bf(float x) {
    union { float f; unsigned u; } v; v.f = x;
    unsigned r = v.u + 0x7FFF + ((v.u >> 16) & 1);   // RNE
    return (ushortT)(r >> 16);
}
__device__ __forceinline__ float lk(float v) { return (v >= 0.f) ? v : 0.1f * v; }

// ---------------------------------------------------------------------------
// 1. bilinear 2x upsample (half-pixel centers, edge clamp) * 2.0  [full batch]
// ---------------------------------------------------------------------------
__global__ __launch_bounds__(256) void upsample_k(const float* __restrict__ in,
                                                  float* __restrict__ out) {
    int gid = blockIdx.x * 256 + threadIdx.x;
    const int total = BB * 4 * IMH * IMW;
    if (gid >= total) return;
    int ox = gid % IMW;
    int t  = gid / IMW;
    int oy = t % IMH;
    int bc = t / IMH;
    const int Hin = IMH / 2, Win = IMW / 2;
    float sy = oy * 0.5f - 0.25f;
    float sx = ox * 0.5f - 0.25f;
    float fy = floorf(sy), fx = floorf(sx);
    float ty_ = sy - fy, tx_ = sx - fx;
    int y0 = (int)fy, x0 = (int)fx;
    int y1 = y0 + 1, x1 = x0 + 1;
    y0 = max(0, min(Hin - 1, y0)); y1 = max(0, min(Hin - 1, y1));
    x0 = max(0, min(Win - 1, x0)); x1 = max(0, min(Win - 1, x1));
    const float* p = in + (long)bc * Hin * Win;
    float v00 = p[y0 * Win + x0], v01 = p[y0 * Win + x1];
    float v10 = p[y1 * Win + x0], v11 = p[y1 * Win + x1];
    float v = (1.f - ty_) * ((1.f - tx_) * v00 + tx_ * v01) +
              ty_ * ((1.f - tx_) * v10 + tx_ * v11);
    out[gid] = 2.f * v;
}

// ---------------------------------------------------------------------------
// 2. zero-init (16B granules)
// ---------------------------------------------------------------------------
__global__ __launch_bounds__(256) void zero4_k(uint4* __restrict__ p, long n) {
    long gid = (long)blockIdx.x * 256 + threadIdx.x;
    long stride = (long)gridDim.x * 256;
    uint4 z = make_uint4(0, 0, 0, 0);
    for (long i = gid; i < n; i += stride) p[i] = z;
}

// ---------------------------------------------------------------------------
// 3. fused NCHW->NHWC transpose + outlier splat.
//    Outlier = corner-events the gather window can't see (|d| > GR), EXACT
//    complement of gather coverage, decided per corner. Rare (~4 sigma).
// ---------------------------------------------------------------------------
__global__ __launch_bounds__(256) void trout_k(const float* __restrict__ feat,
                                               const float* __restrict__ biflow,
                                               int fbase,
                                               float* __restrict__ acc,
                                               float* __restrict__ nhwc, int nb) {
    int gid = blockIdx.x * 256 + threadIdx.x;
    if (gid >= nb * HW_) return;
    int b = gid / HW_;
    int p = gid - b * HW_;
    int y = p / IMW, x = p - y * IMW;

    float f[FC];
#pragma unroll
    for (int c = 0; c < FC; ++c) f[c] = feat[((long)b * FC + c) * HW_ + p];
    float4* dst = (float4*)(nhwc + ((long)b * HW_ + p) * FC);
#pragma unroll
    for (int c4 = 0; c4 < FC / 4; ++c4)
        dst[c4] = make_float4(f[c4 * 4 + 0], f[c4 * 4 + 1],
                              f[c4 * 4 + 2], f[c4 * 4 + 3]);

    const float* fl = biflow + ((long)b * 4 + fbase) * HW_;
    float fx = x + fl[p];
    float fy = y + fl[HW_ + p];
    float x0f = floorf(fx), y0f = floorf(fy);
    int ix0 = (int)x0f, iy0 = (int)y0f;
    if (ix0 >= x - GR && ix0 + 1 <= x + GR && iy0 >= y - GR && iy0 + 1 <= y + GR)
        return;
    float wx1 = fx - x0f, wy1 = fy - y0f;
    float wx0 = 1.f - wx1, wy0 = 1.f - wy1;
    float* accb = acc + (long)b * 33 * HW_;
    const int ixs[4] = {ix0, ix0 + 1, ix0, ix0 + 1};
    const int iys[4] = {iy0, iy0, iy0 + 1, iy0 + 1};
    const float ww[4] = {wx0 * wy0, wx1 * wy0, wx0 * wy1, wx1 * wy1};
#pragma unroll
    for (int k = 0; k < 4; ++k) {
        int ix = ixs[k], iy = iys[k];
        float w = ww[k];
        if (ix < 0 || ix >= IMW || iy < 0 || iy >= IMH || w == 0.f) continue;
        int dx = ix - x, dy = iy - y;
        if (dx >= -GR && dx <= GR && dy >= -GR && dy <= GR) continue;
        int q = iy * IMW + ix;
#pragma unroll
        for (int c = 0; c < FC; ++c) atomicAdd(&accb[c * HW_ + q], f[c] * w);
        atomicAdd(&accb[32 * HW_ + q], w);
    }
}

// ---------------------------------------------------------------------------
// 3c. gather splat + normalize (fused). One thread per OUTPUT pixel.
//     Emits normalized warped features as bf16 directly into the concat
//     section (chOff = 0 for side0, 160 for side1), stride CCH.
// ---------------------------------------------------------------------------
__global__ __launch_bounds__(256) void gather_k(const float* __restrict__ tfeat,
                                                const float* __restrict__ biflow,
                                                int fbase,
                                                const float* __restrict__ acc,
                                                ushortT* __restrict__ concat,
                                                int chOff) {
    const int b = blockIdx.z;
    const int xBase = blockIdx.x * 64;
    const int yBase = blockIdx.y * 4;
    __shared__ float2 sF[20][80];   // 12.8 KB

    const float* fl = biflow + ((long)b * 4 + fbase) * HW_;
    for (int u = threadIdx.x; u < 20 * 80; u += 256) {
        int wy = u / 80, wx = u - wy * 80;
        int gy = yBase - GR + wy, gx = xBase - GR + wx;
        float2 t = make_float2(-1e9f, -1e9f);   // sentinel: never matches
        if ((unsigned)gy < IMH && (unsigned)gx < IMW) {
            int p = gy * IMW + gx;
            t.x = gx + fl[p];        // MUST match trout_k's "x + fl[p]" exactly
            t.y = gy + fl[HW_ + p];
        }
        sF[wy][wx] = t;
    }

    const int lx = threadIdx.x & 63, ly = threadIdx.x >> 6;
    const int ox = xBase + lx, oy = yBase + ly;
    const int q = oy * IMW + ox;
    const float* accb = acc + (long)b * 33 * HW_;

    // init from outlier contributions (mostly zero, cheap coalesced reads)
    float s[FC];
#pragma unroll
    for (int c = 0; c < FC; ++c) s[c] = accb[(long)c * HW_ + q];
    float nsum = accb[(long)32 * HW_ + q];

    __syncthreads();

    const float* tb = tfeat + (long)b * HW_ * FC;
    const int pBase = (yBase - GR + ly) * IMW + (xBase - GR + lx);

    for (int dy = 0; dy < 2 * GR + 1; ++dy) {
#pragma unroll 1
        for (int dx = 0; dx < 2 * GR + 1; ++dx) {
            float2 t = sF[ly + dy][lx + dx];
            float x0f = floorf(t.x), y0f = floorf(t.y);
            int dxm = ox - (int)x0f;
            int dym = oy - (int)y0f;
            if (((unsigned)dxm <= 1u) && ((unsigned)dym <= 1u)) {
                float wx1 = t.x - x0f, wy1 = t.y - y0f;
                float w = (dxm ? wx1 : 1.f - wx1) * (dym ? wy1 : 1.f - wy1);
                if (w != 0.f) {
                    nsum += w;
                    int pp = pBase + dy * IMW + dx;
                    const float4* fp = (const float4*)(tb + (long)pp * FC);
#pragma unroll
                    for (int c4 = 0; c4 < FC / 4; ++c4) {
                        float4 v = fp[c4];
                        s[c4 * 4 + 0] = fmaf(w, v.x, s[c4 * 4 + 0]);
                        s[c4 * 4 + 1] = fmaf(w, v.y, s[c4 * 4 + 1]);
                        s[c4 * 4 + 2] = fmaf(w, v.z, s[c4 * 4 + 2]);
                        s[c4 * 4 + 3] = fmaf(w, v.w, s[c4 * 4 + 3]);
                    }
                }
            }
        }
    }

    float inv = (nsum == 0.f) ? 1.f : (1.f / nsum);
    unsigned pk[16];
#pragma unroll
    for (int k = 0; k < 16; ++k) {
        unsigned lo = f2bf(s[2 * k] * inv);
        unsigned hi = f2bf(s[2 * k + 1] * inv);
        pk[k] = lo | (hi << 16);
    }
    uint4* dst = (uint4*)(concat + ((long)b * HW_ + q) * CCH + chOff);
    dst[0] = *(uint4*)&pk[0];
    dst[1] = *(uint4*)&pk[4];
    dst[2] = *(uint4*)&pk[8];
    dst[3] = *(uint4*)&pk[12];
}

// ---------------------------------------------------------------------------
// 4. temporal features fp32 NCHW -> bf16 into concat ch32..63 (ftf) and
//    ch192..223 (btf)
// ---------------------------------------------------------------------------
__global__ __launch_bounds__(256) void tconv_k(const float* __restrict__ ftf,
                                               const float* __restrict__ btf,
                                               ushortT* __restrict__ concat, int nb) {
    int gid = blockIdx.x * 256 + threadIdx.x;
    if (gid >= nb * HW_ * 8) return;
    int c8 = gid & 7;
    int t = gid >> 3;
    int p = t % HW_;
    int b = t / HW_;
    int ch = c8 * 8;                 // 0..63
    const float* src = (ch < 32) ? ftf + ((long)b * 32 + ch) * HW_ + p
                                 : btf + ((long)b * 32 + (ch - 32)) * HW_ + p;
    int chp = (ch < 32) ? (32 + ch) : (192 + (ch - 32));
    ushortT pk[8];
#pragma unroll
    for (int j = 0; j < 8; ++j) pk[j] = f2bf(src[(long)j * HW_]);
    *(uint4*)&concat[((long)b * HW_ + p) * CCH + chp] = *(uint4*)pk;
}

// ---------------------------------------------------------------------------
// 5. correlation volume (9x9, mean over 32 ch) + leaky -> concat ch64..159.
//    LDS-tiled from concat's p1-feat section. Tile 32x8 px; window 40x16 px.
//    Slot layout 64 + dy*10 + dx (dx=9 and ch154..159 zeroed).
// ---------------------------------------------------------------------------
__global__ __launch_bounds__(256) void corr_k(ushortT* __restrict__ concat) {
    const int b = blockIdx.z;
    const int xB = blockIdx.x * 32;
    const int yB = blockIdx.y * 8;
    __shared__ char sW[16 * 40 * 72];   // 46080 B

    const long pixBase = (long)b * HW_;

    for (int u = threadIdx.x; u < 16 * 40 * 8; u += 256) {
        int qq = u & 7;
        int site = u >> 3;
        int row = site / 40, col = site - row * 40;
        int gy = yB - 4 + row, gx = xB - 4 + col;
        uint2 v = make_uint2(0u, 0u);
        if ((unsigned)gy < IMH && (unsigned)gx < IMW)
            v = *(const uint2*)(concat + (pixBase + (long)gy * IMW + gx) * CCH + 160 + qq * 4);
        *(uint2*)(sW + site * 72 + qq * 8) = v;
    }

    const int lx = threadIdx.x & 31, ly = threadIdx.x >> 5;
    const int ox = xB + lx, oy = yB + ly;

    unsigned wr[16];
    {
        const uint4* wp = (const uint4*)(concat + (pixBase + (long)oy * IMW + ox) * CCH);
        *(uint4*)&wr[0]  = wp[0];
        *(uint4*)&wr[4]  = wp[1];
        *(uint4*)&wr[8]  = wp[2];
        *(uint4*)&wr[12] = wp[3];
    }
    float w0f[32];
#pragma unroll
    for (int k = 0; k < 16; ++k) {
        union { unsigned u; float f; } lo, hi;
        lo.u = wr[k] << 16;
        hi.u = wr[k] & 0xffff0000u;
        w0f[2 * k]     = lo.f;
        w0f[2 * k + 1] = hi.f;
    }

    __syncthreads();

    const char* lbase = sW + (ly * 40 + lx) * 72;
    unsigned* ob = (unsigned*)concat + (pixBase + (long)oy * IMW + ox) * (CCH / 2) + 32;

    for (int dy = 0; dy < 9; ++dy) {
        const char* rp = lbase + dy * (40 * 72);
        unsigned pd[5] = {0, 0, 0, 0, 0};
#pragma unroll
        for (int dx = 0; dx < 9; ++dx) {
            float s0 = 0.f, s1 = 0.f, s2 = 0.f, s3 = 0.f;
#pragma unroll
            for (int k = 0; k < 8; k += 2) {
                uint2 va = *(const uint2*)(rp + dx * 72 + k * 8);
                uint2 vb = *(const uint2*)(rp + dx * 72 + k * 8 + 8);
                union { unsigned u; float f; } c0, c1, c2, c3, d0, d1, d2, d3;
                c0.u = va.x << 16; c1.u = va.x & 0xffff0000u;
                c2.u = va.y << 16; c3.u = va.y & 0xffff0000u;
                d0.u = vb.x << 16; d1.u = vb.x & 0xffff0000u;
                d2.u = vb.y << 16; d3.u = vb.y & 0xffff0000u;
                s0 = fmaf(w0f[4 * k + 0], c0.f, s0);
                s1 = fmaf(w0f[4 * k + 1], c1.f, s1);
                s2 = fmaf(w0f[4 * k + 2], c2.f, s2);
                s3 = fmaf(w0f[4 * k + 3], c3.f, s3);
                s0 = fmaf(w0f[4 * k + 4], d0.f, s0);
                s1 = fmaf(w0f[4 * k + 5], d1.f, s1);
                s2 = fmaf(w0f[4 * k + 6], d2.f, s2);
                s3 = fmaf(w0f[4 * k + 7], d3.f, s3);
            }
            float s = ((s0 + s1) + (s2 + s3)) * (1.f / 32.f);
            s = lk(s);
            unsigned bf = f2bf(s);
            if (dx & 1) pd[dx >> 1] |= bf << 16;
            else        pd[dx >> 1] = bf;
        }
#pragma unroll
        for (int j = 0; j < 5; ++j) ob[dy * 5 + j] = pd[j];
    }
    ob[45] = 0u; ob[46] = 0u; ob[47] = 0u;   // ch154..159 zero (NaN-safe pad)
}

// ---------------------------------------------------------------------------
// 7a. weight transform (generic): W[oc][cin][3][3] fp32 -> Wb[tap][ocp][cinp]
// ---------------------------------------------------------------------------
__global__ __launch_bounds__(256) void wconv_k(const float* __restrict__ W,
                                               ushortT* __restrict__ dst,
                                               int OC, int OCp, int CIN, int CINp) {
    int gid = blockIdx.x * 256 + threadIdx.x;
    int total = 9 * OCp * CINp;
    if (gid >= total) return;
    int cin = gid % CINp;
    int t = gid / CINp;
    int oc = t % OCp;
    int tap = t / OCp;
    float v = 0.f;
    if (oc < OC && cin < CIN) v = W[((long)oc * CIN + cin) * 9 + tap];
    dst[gid] = f2bf(v);
}

// ---------------------------------------------------------------------------
// 7b. L1 weight transform with concat channel permutation.
//     mode 0 (pass0, act = concat+0):  cin' 0..63 feat, 64..159 corr slots
//     mode 1 (pass1, act = concat+64): cin' 0..95 corr slots, 96..159 feat
//     corr slot s = dy*10+dx -> W cin 64+dy*9+dx (dx<9, dy<9), else zero
// ---------------------------------------------------------------------------
__global__ __launch_bounds__(256) void wconv1_k(const float* __restrict__ W,
                                                ushortT* __restrict__ dst, int mode) {
    int gid = blockIdx.x * 256 + threadIdx.x;
    const int total = 9 * 64 * 160;
    if (gid >= total) return;
    int cin = gid % 160;
    int t = gid / 160;
    int oc = t % 64;
    int tap = t / 64;
    int src = -1;
    if (mode == 0) {
        if (cin < 64) src = cin;
        else {
            int tt = cin - 64;            // 0..95
            int dy = tt / 10, dx = tt - dy * 10;
            if (dy < 9 && dx < 9) src = 64 + dy * 9 + dx;
        }
    } else {
        if (cin < 96) {
            int dy = cin / 10, dx = cin - dy * 10;
            if (dy < 9 && dx < 9) src = 64 + dy * 9 + dx;
        } else {
            src = cin - 96;
        }
    }
    float v = 0.f;
    if (src >= 0) v = W[((long)oc * 145 + src) * 9 + tap];
    dst[gid] = f2bf(v);
}

// ---------------------------------------------------------------------------
// 8. MFMA implicit-GEMM conv3x3 (SAME). Block = 256 thr = 4 waves.
//    Tile = 4 rows x 32 px (grid 10x48xnb = 960 blocks); wave wv owns row
//    y0+wv (2 N-tiles of 16 px), loops MT M-tiles (16 oc each).
//    Single-barrier double-buffered K pipeline: prefetch kc+1 into regs
//    before the barrier, compute kc from LDS[cur], ds_write to LDS[cur^1].
//    LDS site stride = 40 ushort (80 B): 16B-aligned b128 ops, 2-way banks.
//    All pads are zero-weighted (inputs finite), so no cin masking.
// ---------------------------------------------------------------------------
#define SUNITS (6 * 34 * 4)   // 816 16B-chunks per K-chunk stage

template <int MT, int KC, bool LK, bool FIN>
__global__ __launch_bounds__(256) void mconv_k(
    const ushortT* __restrict__ act, int actStride,
    const ushortT* __restrict__ Wb,
    ushortT* __restrict__ outp, int outStride,
    const float* __restrict__ bfp, float* __restrict__ fout, int chBase) {

    const int CINp = KC * 32;
    const int OCp = MT * 16;
    const int tid = threadIdx.x;
    const int lane = tid & 63;
    const int wv = tid >> 6;
    const int l15 = lane & 15;
    const int quad = lane >> 4;
    const int x0 = blockIdx.x * 32;    // 10 tiles
    const int y0 = blockIdx.y * 4;     // 48 tiles
    const int b = blockIdx.z;          // local batch

    __shared__ ushortT sAct[2][6 * 34 * 40];   // 2 x 16320 B

    f32x4 acc[MT][2];
#pragma unroll
    for (int i = 0; i < MT; ++i)
#pragma unroll
        for (int j = 0; j < 2; ++j) acc[i][j] = (f32x4)0.f;

    const long pixBase = (long)b * HW_;

    uint4 rg[4];
    auto prefetch = [&](int kc) {
#pragma unroll
        for (int k = 0; k < 4; ++k) {
            int u = tid + k * 256;
            if (u < SUNITS) {
                int c8 = u & 3;
                int site = u >> 2;
                int ky = site / 34;
                int xi = site - ky * 34;
                int gy = y0 + ky - 1;
                int gx = x0 + xi - 1;
                uint4 v = make_uint4(0, 0, 0, 0);
                if ((unsigned)gy < IMH && (unsigned)gx < IMW)
                    v = *(const uint4*)(act + ((pixBase + (long)gy * IMW + gx) * actStride + kc * 32 + c8 * 8));
                rg[k] = v;
            }
        }
    };
    auto commit = [&](int buf) {
#pragma unroll
        for (int k = 0; k < 4; ++k) {
            int u = tid + k * 256;
            if (u < SUNITS) {
                int c8 = u & 3;
                int site = u >> 2;
                *(uint4*)&sAct[buf][site * 40 + c8 * 8] = rg[k];
            }
        }
    };

    prefetch(0);
    commit(0);
    int cur = 0;

    for (int kc = 0; kc < KC; ++kc) {
        if (kc + 1 < KC) prefetch(kc + 1);
        __syncthreads();
#pragma unroll
        for (int tap = 0; tap < 9; ++tap) {
            const int ky = tap / 3, kx = tap % 3;
            const int rowb = (wv + ky) * 34;
            FragU bf[2];
#pragma unroll
            for (int nt = 0; nt < 2; ++nt)
                bf[nt].u = *(const uint4*)&sAct[cur][(rowb + nt * 16 + l15 + kx) * 40 + quad * 8];
            const ushortT* wp = Wb + (((long)tap * OCp + l15) * CINp + kc * 32 + quad * 8);
#pragma unroll
            for (int mt = 0; mt < MT; ++mt) {
                FragU af;
                af.u = *(const uint4*)(wp + (long)mt * 16 * CINp);
#pragma unroll
                for (int nt = 0; nt < 2; ++nt)
                    acc[mt][nt] = __builtin_amdgcn_mfma_f32_16x16x32_bf16(af.s8, bf[nt].s8, acc[mt][nt], 0, 0, 0);
            }
        }
        if (kc + 1 < KC) commit(cur ^ 1);
        cur ^= 1;
    }

    const int yo = y0 + wv;
    if (FIN) {
        if (quad == 0) {
#pragma unroll
            for (int nt = 0; nt < 2; ++nt) {
                int px = x0 + nt * 16 + l15;
#pragma unroll
                for (int r = 0; r < 2; ++r) {
                    float v = lk(acc[0][nt][r]);
                    long o = ((long)(b * 4 + chBase + r) * IMH + yo) * IMW + px;
                    fout[o] = bfp[o] + v;
                }
            }
        }
    } else {
        const long rowBase = (pixBase + (long)yo * IMW) * outStride;
#pragma unroll
        for (int nt = 0; nt < 2; ++nt) {
            long obase = rowBase + (long)(x0 + nt * 16 + l15) * outStride;
#pragma unroll
            for (int mt = 0; mt < MT; ++mt) {
                int oc = mt * 16 + quad * 4;
                ushortT pk[4];
#pragma unroll
                for (int r = 0; r < 4; ++r) {
                    float v = acc[mt][nt][r];
                    if (LK) v = lk(v);
                    pk[r] = f2bf(v);
                }
                *(uint2*)&outp[obase + oc] = *(uint2*)pk;
            }
        }
    }
}

// ---------------------------------------------------------------------------
// launch — ws-size-adaptive batch grouping
// ---------------------------------------------------------------------------
extern "C" void kernel_launch(void* const* d_in, const int* in_sizes, int n_in,
                              void* d_out, int out_size, void* d_ws, size_t ws_size,
                              hipStream_t stream) {
    const float* f0  = (const float*)d_in[0];
    const float* f1  = (const float*)d_in[1];
    const float* bfp = (const float*)d_in[2];
    const float* ftf = (const float*)d_in[3];
    const float* btf = (const float*)d_in[4];
    const float* W1  = (const float*)d_in[5];
    const float* W2  = (const float*)d_in[6];
    const float* W3  = (const float*)d_in[7];
    const float* W4  = (const float*)d_in[8];
    const float* W5  = (const float*)d_in[9];
    const float* W6  = (const float*)d_in[10];
    const float* W7  = (const float*)d_in[11];
    float* out = (float*)d_out;

    char* base = (char*)d_ws;
    size_t off = 0;
    auto alloc = [&](size_t bytes) { char* p = base + off; off += (bytes + 255) & ~(size_t)255; return p; };

    float* biflow = (float*)alloc((size_t)BB * 4 * HW_ * 4);
    ushortT* WbL1a = (ushortT*)alloc((size_t)9 * 64 * 160 * 2);
    ushortT* WbL1b = (ushortT*)alloc((size_t)9 * 64 * 160 * 2);
    ushortT* WbL2 = (ushortT*)alloc((size_t)9 * 64 * 64 * 2);
    ushortT* WbL3 = (ushortT*)alloc((size_t)9 * 64 * 64 * 2);
    ushortT* WbL4 = (ushortT*)alloc((size_t)9 * 32 * 64 * 2);
    ushortT* WbL5 = (ushortT*)alloc((size_t)9 * 32 * 32 * 2);
    ushortT* WbL6 = (ushortT*)alloc((size_t)9 * 16 * 32 * 2);
    ushortT* WbL7 = (ushortT*)alloc((size_t)9 * 16 * 32 * 2);

    // per-batch bytes/px: acc0+acc1(264) + concat(448) + bufA(128) + bufB(128) = 968
    const size_t PERB = (size_t)968 * HW_;
    size_t remain = (ws_size > off + 4096) ? (ws_size - off - 4096) : 0;
    int NB = (int)(remain / (PERB + 4096));
    if (NB < 1) NB = 1;
    if (NB > BB) NB = BB;

    float*   acc0   = (float*)alloc((size_t)NB * 33 * HW_ * 4);
    float*   acc1   = (float*)alloc((size_t)NB * 33 * HW_ * 4);
    ushortT* concat = (ushortT*)alloc((size_t)NB * HW_ * CCH * 2);
    ushortT* bufA   = (ushortT*)alloc((size_t)NB * HW_ * 64 * 2);   // aliased: NB*HW*32 fp32 NHWC
    ushortT* bufB   = (ushortT*)alloc((size_t)NB * HW_ * 64 * 2);

    upsample_k<<<(BB * 4 * HW_ + 255) / 256, 256, 0, stream>>>(bfp, biflow);

    wconv1_k<<<(9 * 64 * 160 + 255) / 256, 256, 0, stream>>>(W1, WbL1a, 0);
    wconv1_k<<<(9 * 64 * 160 + 255) / 256, 256, 0, stream>>>(W1, WbL1b, 1);
    wconv_k<<<(9 * 64 * 64 + 255) / 256, 256, 0, stream>>>(W2, WbL2, 64, 64, 64, 64);
    wconv_k<<<(9 * 64 * 64 + 255) / 256, 256, 0, stream>>>(W3, WbL3, 64, 64, 64, 64);
    wconv_k<<<(9 * 32 * 64 + 255) / 256, 256, 0, stream>>>(W4, WbL4, 32, 32, 64, 64);
    wconv_k<<<(9 * 32 * 32 + 255) / 256, 256, 0, stream>>>(W5, WbL5, 32, 32, 32, 32);
    wconv_k<<<(9 * 16 * 32 + 255) / 256, 256, 0, stream>>>(W6, WbL6, 16, 16, 32, 32);
    wconv_k<<<(9 * 16 * 32 + 255) / 256, 256, 0, stream>>>(W7, WbL7, 2, 16, 16, 32);

    for (int g = 0; g < BB; g += NB) {
        const int nb = (BB - g < NB) ? (BB - g) : NB;
        const int npix = nb * HW_;
        const float* f0g  = f0 + (size_t)g * FC * HW_;
        const float* f1g  = f1 + (size_t)g * FC * HW_;
        const float* ftfg = ftf + (size_t)g * FC * HW_;
        const float* btfg = btf + (size_t)g * FC * HW_;
        const float* bflg = biflow + (size_t)g * 4 * HW_;
        float* outg = out + (size_t)g * 4 * HW_;

        // zero both acc regions (contiguous) in one dispatch
        zero4_k<<<2048, 256, 0, stream>>>((uint4*)acc0, (long)NB * 66 * HW_ / 4);

        // fused transpose + outlier splat
        trout_k<<<(npix + 255) / 256, 256, 0, stream>>>(f0g, bflg, 0, acc0, (float*)bufA, nb);
        trout_k<<<(npix + 255) / 256, 256, 0, stream>>>(f1g, bflg, 2, acc1, (float*)bufB, nb);

        dim3 gg(IMW / 64, IMH / 4, nb);
        gather_k<<<gg, 256, 0, stream>>>((const float*)bufA, bflg, 0, acc0, concat, 0);
        gather_k<<<gg, 256, 0, stream>>>((const float*)bufB, bflg, 2, acc1, concat, 160);

        tconv_k<<<(npix * 8 + 255) / 256, 256, 0, stream>>>(ftfg, btfg, concat, nb);

        dim3 cgrid(IMW / 32, IMH / 8, nb);
        corr_k<<<cgrid, 256, 0, stream>>>(concat);

        dim3 cg(10, 48, nb);
        for (int pass = 0; pass < 2; ++pass) {
            const ushortT* actL1 = concat + (pass ? 64 : 0);
            const ushortT* WbL1 = pass ? WbL1b : WbL1a;
            int chB = pass ? 2 : 0;
            mconv_k<4, 5, false, false><<<cg, 256, 0, stream>>>(actL1, CCH, WbL1, bufA, 64, nullptr, nullptr, 0);
            mconv_k<4, 2, false, false><<<cg, 256, 0, stream>>>(bufA, 64, WbL2, bufB, 64, nullptr, nullptr, 0);
            mconv_k<4, 2, true,  false><<<cg, 256, 0, stream>>>(bufB, 64, WbL3, bufA, 64, nullptr, nullptr, 0);
            mconv_k<2, 2, false, false><<<cg, 256, 0, stream>>>(bufA, 64, WbL4, bufB, 32, nullptr, nullptr, 0);
            mconv_k<2, 1, false, false><<<cg, 256, 0, stream>>>(bufB, 32, WbL5, bufA, 32, nullptr, nullptr, 0);
            mconv_k<1, 1, false, false><<<cg, 256, 0, stream>>>(bufA, 32, WbL6, bufB, 16, nullptr, nullptr, 0);
            mconv_k<1, 1, true,  true ><<<cg, 256, 0, stream>>>(bufB, 16, WbL7, nullptr, 0, bflg, outg, chB);
        }
    }
}

// Round 5
// 2020.665 us; speedup vs baseline: 1.0787x; 1.0787x over previous
//
#include <hip/hip_runtime.h>

// Problem constants (B=8, C=32, H=192, W=320)
#define IMH 192
#define IMW 320
#define HW_ (IMH * IMW)      // 61440
#define BB 8
#define FC 32
#define GR 8                 // gather radius: covers |disp| < 8 (~4 sigma)
#define CCH 224              // concat channels/px: [p0 feat 64][corr 96][p1 feat 64]

typedef unsigned short ushortT;
typedef __attribute__((ext_vector_type(8))) short short8;   // 8 bf16 = 4 VGPRs
typedef __attribute__((ext_vector_type(4))) float f32x4;

union FragU { uint4 u; short8 s8; };

__device__ __forceinline__ ushortT f2bf(float x) {
    union { float f; unsigned u; } v; v.f = x;
    unsigned r = v.u + 0x7FFF + ((v.u >> 16) & 1);   // RNE
    return (ushortT)(r >> 16);
}
__device__ __forceinline__ float lk(float v) { return (v >= 0.f) ? v : 0.1f * v; }

// ---------------------------------------------------------------------------
// 1. bilinear 2x upsample (half-pixel centers, edge clamp) * 2.0  [full batch]
// ---------------------------------------------------------------------------
__global__ __launch_bounds__(256) void upsample_k(const float* __restrict__ in,
                                                  float* __restrict__ out) {
    int gid = blockIdx.x * 256 + threadIdx.x;
    const int total = BB * 4 * IMH * IMW;
    if (gid >= total) return;
    int ox = gid % IMW;
    int t  = gid / IMW;
    int oy = t % IMH;
    int bc = t / IMH;
    const int Hin = IMH / 2, Win = IMW / 2;
    float sy = oy * 0.5f - 0.25f;
    float sx = ox * 0.5f - 0.25f;
    float fy = floorf(sy), fx = floorf(sx);
    float ty_ = sy - fy, tx_ = sx - fx;
    int y0 = (int)fy, x0 = (int)fx;
    int y1 = y0 + 1, x1 = x0 + 1;
    y0 = max(0, min(Hin - 1, y0)); y1 = max(0, min(Hin - 1, y1));
    x0 = max(0, min(Win - 1, x0)); x1 = max(0, min(Win - 1, x1));
    const float* p = in + (long)bc * Hin * Win;
    float v00 = p[y0 * Win + x0], v01 = p[y0 * Win + x1];
    float v10 = p[y1 * Win + x0], v11 = p[y1 * Win + x1];
    float v = (1.f - ty_) * ((1.f - tx_) * v00 + tx_ * v01) +
              ty_ * ((1.f - tx_) * v10 + tx_ * v11);
    out[gid] = 2.f * v;
}

// ---------------------------------------------------------------------------
// 2. zero-init (16B granules)
// ---------------------------------------------------------------------------
__global__ __launch_bounds__(256) void zero4_k(uint4* __restrict__ p, long n) {
    long gid = (long)blockIdx.x * 256 + threadIdx.x;
    long stride = (long)gridDim.x * 256;
    uint4 z = make_uint4(0, 0, 0, 0);
    for (long i = gid; i < n; i += stride) p[i] = z;
}

// ---------------------------------------------------------------------------
// 3. fused NCHW->NHWC transpose + outlier splat.
//    Outlier = corner-events the gather window can't see (|d| > GR), EXACT
//    complement of gather coverage, decided per corner. Rare (~4 sigma).
// ---------------------------------------------------------------------------
__global__ __launch_bounds__(256) void trout_k(const float* __restrict__ feat,
                                               const float* __restrict__ biflow,
                                               int fbase,
                                               float* __restrict__ acc,
                                               float* __restrict__ nhwc, int nb) {
    int gid = blockIdx.x * 256 + threadIdx.x;
    if (gid >= nb * HW_) return;
    int b = gid / HW_;
    int p = gid - b * HW_;
    int y = p / IMW, x = p - y * IMW;

    float f[FC];
#pragma unroll
    for (int c = 0; c < FC; ++c) f[c] = feat[((long)b * FC + c) * HW_ + p];
    float4* dst = (float4*)(nhwc + ((long)b * HW_ + p) * FC);
#pragma unroll
    for (int c4 = 0; c4 < FC / 4; ++c4)
        dst[c4] = make_float4(f[c4 * 4 + 0], f[c4 * 4 + 1],
                              f[c4 * 4 + 2], f[c4 * 4 + 3]);

    const float* fl = biflow + ((long)b * 4 + fbase) * HW_;
    float fx = x + fl[p];
    float fy = y + fl[HW_ + p];
    float x0f = floorf(fx), y0f = floorf(fy);
    int ix0 = (int)x0f, iy0 = (int)y0f;
    if (ix0 >= x - GR && ix0 + 1 <= x + GR && iy0 >= y - GR && iy0 + 1 <= y + GR)
        return;
    float wx1 = fx - x0f, wy1 = fy - y0f;
    float wx0 = 1.f - wx1, wy0 = 1.f - wy1;
    float* accb = acc + (long)b * 33 * HW_;
    const int ixs[4] = {ix0, ix0 + 1, ix0, ix0 + 1};
    const int iys[4] = {iy0, iy0, iy0 + 1, iy0 + 1};
    const float ww[4] = {wx0 * wy0, wx1 * wy0, wx0 * wy1, wx1 * wy1};
#pragma unroll
    for (int k = 0; k < 4; ++k) {
        int ix = ixs[k], iy = iys[k];
        float w = ww[k];
        if (ix < 0 || ix >= IMW || iy < 0 || iy >= IMH || w == 0.f) continue;
        int dx = ix - x, dy = iy - y;
        if (dx >= -GR && dx <= GR && dy >= -GR && dy <= GR) continue;
        int q = iy * IMW + ix;
#pragma unroll
        for (int c = 0; c < FC; ++c) atomicAdd(&accb[c * HW_ + q], f[c] * w);
        atomicAdd(&accb[32 * HW_ + q], w);
    }
}

// ---------------------------------------------------------------------------
// 3c. gather splat + normalize (fused). One thread per OUTPUT pixel.
//     Emits normalized warped features as bf16 directly into the concat
//     section (chOff = 0 for side0, 160 for side1), stride CCH.
// ---------------------------------------------------------------------------
__global__ __launch_bounds__(256) void gather_k(const float* __restrict__ tfeat,
                                                const float* __restrict__ biflow,
                                                int fbase,
                                                const float* __restrict__ acc,
                                                ushortT* __restrict__ concat,
                                                int chOff) {
    const int b = blockIdx.z;
    const int xBase = blockIdx.x * 64;
    const int yBase = blockIdx.y * 4;
    __shared__ float2 sF[20][80];   // 12.8 KB

    const float* fl = biflow + ((long)b * 4 + fbase) * HW_;
    for (int u = threadIdx.x; u < 20 * 80; u += 256) {
        int wy = u / 80, wx = u - wy * 80;
        int gy = yBase - GR + wy, gx = xBase - GR + wx;
        float2 t = make_float2(-1e9f, -1e9f);   // sentinel: never matches
        if ((unsigned)gy < IMH && (unsigned)gx < IMW) {
            int p = gy * IMW + gx;
            t.x = gx + fl[p];        // MUST match trout_k's "x + fl[p]" exactly
            t.y = gy + fl[HW_ + p];
        }
        sF[wy][wx] = t;
    }

    const int lx = threadIdx.x & 63, ly = threadIdx.x >> 6;
    const int ox = xBase + lx, oy = yBase + ly;
    const int q = oy * IMW + ox;
    const float* accb = acc + (long)b * 33 * HW_;

    // init from outlier contributions (mostly zero, cheap coalesced reads)
    float s[FC];
#pragma unroll
    for (int c = 0; c < FC; ++c) s[c] = accb[(long)c * HW_ + q];
    float nsum = accb[(long)32 * HW_ + q];

    __syncthreads();

    const float* tb = tfeat + (long)b * HW_ * FC;
    const int pBase = (yBase - GR + ly) * IMW + (xBase - GR + lx);

    for (int dy = 0; dy < 2 * GR + 1; ++dy) {
#pragma unroll 1
        for (int dx = 0; dx < 2 * GR + 1; ++dx) {
            float2 t = sF[ly + dy][lx + dx];
            float x0f = floorf(t.x), y0f = floorf(t.y);
            int dxm = ox - (int)x0f;
            int dym = oy - (int)y0f;
            if (((unsigned)dxm <= 1u) && ((unsigned)dym <= 1u)) {
                float wx1 = t.x - x0f, wy1 = t.y - y0f;
                float w = (dxm ? wx1 : 1.f - wx1) * (dym ? wy1 : 1.f - wy1);
                if (w != 0.f) {
                    nsum += w;
                    int pp = pBase + dy * IMW + dx;
                    const float4* fp = (const float4*)(tb + (long)pp * FC);
#pragma unroll
                    for (int c4 = 0; c4 < FC / 4; ++c4) {
                        float4 v = fp[c4];
                        s[c4 * 4 + 0] = fmaf(w, v.x, s[c4 * 4 + 0]);
                        s[c4 * 4 + 1] = fmaf(w, v.y, s[c4 * 4 + 1]);
                        s[c4 * 4 + 2] = fmaf(w, v.z, s[c4 * 4 + 2]);
                        s[c4 * 4 + 3] = fmaf(w, v.w, s[c4 * 4 + 3]);
                    }
                }
            }
        }
    }

    float inv = (nsum == 0.f) ? 1.f : (1.f / nsum);
    unsigned pk[16];
#pragma unroll
    for (int k = 0; k < 16; ++k) {
        unsigned lo = f2bf(s[2 * k] * inv);
        unsigned hi = f2bf(s[2 * k + 1] * inv);
        pk[k] = lo | (hi << 16);
    }
    uint4* dst = (uint4*)(concat + ((long)b * HW_ + q) * CCH + chOff);
    dst[0] = *(uint4*)&pk[0];
    dst[1] = *(uint4*)&pk[4];
    dst[2] = *(uint4*)&pk[8];
    dst[3] = *(uint4*)&pk[12];
}

// ---------------------------------------------------------------------------
// 4. temporal features fp32 NCHW -> bf16 into concat ch32..63 (ftf) and
//    ch192..223 (btf)
// ---------------------------------------------------------------------------
__global__ __launch_bounds__(256) void tconv_k(const float* __restrict__ ftf,
                                               const float* __restrict__ btf,
                                               ushortT* __restrict__ concat, int nb) {
    int gid = blockIdx.x * 256 + threadIdx.x;
    if (gid >= nb * HW_ * 8) return;
    int c8 = gid & 7;
    int t = gid >> 3;
    int p = t % HW_;
    int b = t / HW_;
    int ch = c8 * 8;                 // 0..63
    const float* src = (ch < 32) ? ftf + ((long)b * 32 + ch) * HW_ + p
                                 : btf + ((long)b * 32 + (ch - 32)) * HW_ + p;
    int chp = (ch < 32) ? (32 + ch) : (192 + (ch - 32));
    ushortT pk[8];
#pragma unroll
    for (int j = 0; j < 8; ++j) pk[j] = f2bf(src[(long)j * HW_]);
    *(uint4*)&concat[((long)b * HW_ + p) * CCH + chp] = *(uint4*)pk;
}

// ---------------------------------------------------------------------------
// 5. correlation volume (9x9, mean over 32 ch) + leaky -> concat ch64..159.
//    LDS-tiled from concat's p1-feat section. Tile 32x8 px; window 40x16 px.
//    Slot layout 64 + dy*10 + dx (dx=9 and ch154..159 zeroed).
// ---------------------------------------------------------------------------
__global__ __launch_bounds__(256) void corr_k(ushortT* __restrict__ concat) {
    const int b = blockIdx.z;
    const int xB = blockIdx.x * 32;
    const int yB = blockIdx.y * 8;
    __shared__ char sW[16 * 40 * 72];   // 46080 B

    const long pixBase = (long)b * HW_;

    for (int u = threadIdx.x; u < 16 * 40 * 8; u += 256) {
        int qq = u & 7;
        int site = u >> 3;
        int row = site / 40, col = site - row * 40;
        int gy = yB - 4 + row, gx = xB - 4 + col;
        uint2 v = make_uint2(0u, 0u);
        if ((unsigned)gy < IMH && (unsigned)gx < IMW)
            v = *(const uint2*)(concat + (pixBase + (long)gy * IMW + gx) * CCH + 160 + qq * 4);
        *(uint2*)(sW + site * 72 + qq * 8) = v;
    }

    const int lx = threadIdx.x & 31, ly = threadIdx.x >> 5;
    const int ox = xB + lx, oy = yB + ly;

    unsigned wr[16];
    {
        const uint4* wp = (const uint4*)(concat + (pixBase + (long)oy * IMW + ox) * CCH);
        *(uint4*)&wr[0]  = wp[0];
        *(uint4*)&wr[4]  = wp[1];
        *(uint4*)&wr[8]  = wp[2];
        *(uint4*)&wr[12] = wp[3];
    }
    float w0f[32];
#pragma unroll
    for (int k = 0; k < 16; ++k) {
        union { unsigned u; float f; } lo, hi;
        lo.u = wr[k] << 16;
        hi.u = wr[k] & 0xffff0000u;
        w0f[2 * k]     = lo.f;
        w0f[2 * k + 1] = hi.f;
    }

    __syncthreads();

    const char* lbase = sW + (ly * 40 + lx) * 72;
    unsigned* ob = (unsigned*)concat + (pixBase + (long)oy * IMW + ox) * (CCH / 2) + 32;

    for (int dy = 0; dy < 9; ++dy) {
        const char* rp = lbase + dy * (40 * 72);
        unsigned pd[5] = {0, 0, 0, 0, 0};
#pragma unroll
        for (int dx = 0; dx < 9; ++dx) {
            float s0 = 0.f, s1 = 0.f, s2 = 0.f, s3 = 0.f;
#pragma unroll
            for (int k = 0; k < 8; k += 2) {
                uint2 va = *(const uint2*)(rp + dx * 72 + k * 8);
                uint2 vb = *(const uint2*)(rp + dx * 72 + k * 8 + 8);
                union { unsigned u; float f; } c0, c1, c2, c3, d0, d1, d2, d3;
                c0.u = va.x << 16; c1.u = va.x & 0xffff0000u;
                c2.u = va.y << 16; c3.u = va.y & 0xffff0000u;
                d0.u = vb.x << 16; d1.u = vb.x & 0xffff0000u;
                d2.u = vb.y << 16; d3.u = vb.y & 0xffff0000u;
                s0 = fmaf(w0f[4 * k + 0], c0.f, s0);
                s1 = fmaf(w0f[4 * k + 1], c1.f, s1);
                s2 = fmaf(w0f[4 * k + 2], c2.f, s2);
                s3 = fmaf(w0f[4 * k + 3], c3.f, s3);
                s0 = fmaf(w0f[4 * k + 4], d0.f, s0);
                s1 = fmaf(w0f[4 * k + 5], d1.f, s1);
                s2 = fmaf(w0f[4 * k + 6], d2.f, s2);
                s3 = fmaf(w0f[4 * k + 7], d3.f, s3);
            }
            float s = ((s0 + s1) + (s2 + s3)) * (1.f / 32.f);
            s = lk(s);
            unsigned bf = f2bf(s);
            if (dx & 1) pd[dx >> 1] |= bf << 16;
            else        pd[dx >> 1] = bf;
        }
#pragma unroll
        for (int j = 0; j < 5; ++j) ob[dy * 5 + j] = pd[j];
    }
    ob[45] = 0u; ob[46] = 0u; ob[47] = 0u;   // ch154..159 zero (NaN-safe pad)
}

// ---------------------------------------------------------------------------
// 7a. weight transform (generic): W[oc][cin][3][3] fp32 -> Wb[tap][ocp][cinp]
// ---------------------------------------------------------------------------
__global__ __launch_bounds__(256) void wconv_k(const float* __restrict__ W,
                                               ushortT* __restrict__ dst,
                                               int OC, int OCp, int CIN, int CINp) {
    int gid = blockIdx.x * 256 + threadIdx.x;
    int total = 9 * OCp * CINp;
    if (gid >= total) return;
    int cin = gid % CINp;
    int t = gid / CINp;
    int oc = t % OCp;
    int tap = t / OCp;
    float v = 0.f;
    if (oc < OC && cin < CIN) v = W[((long)oc * CIN + cin) * 9 + tap];
    dst[gid] = f2bf(v);
}

// ---------------------------------------------------------------------------
// 7b. L1 weight transform with concat channel permutation.
//     mode 0 (pass0, act = concat+0):  cin' 0..63 feat, 64..159 corr slots
//     mode 1 (pass1, act = concat+64): cin' 0..95 corr slots, 96..159 feat
//     corr slot s = dy*10+dx -> W cin 64+dy*9+dx (dx<9, dy<9), else zero
// ---------------------------------------------------------------------------
__global__ __launch_bounds__(256) void wconv1_k(const float* __restrict__ W,
                                                ushortT* __restrict__ dst, int mode) {
    int gid = blockIdx.x * 256 + threadIdx.x;
    const int total = 9 * 64 * 160;
    if (gid >= total) return;
    int cin = gid % 160;
    int t = gid / 160;
    int oc = t % 64;
    int tap = t / 64;
    int src = -1;
    if (mode == 0) {
        if (cin < 64) src = cin;
        else {
            int tt = cin - 64;            // 0..95
            int dy = tt / 10, dx = tt - dy * 10;
            if (dy < 9 && dx < 9) src = 64 + dy * 9 + dx;
        }
    } else {
        if (cin < 96) {
            int dy = cin / 10, dx = cin - dy * 10;
            if (dy < 9 && dx < 9) src = 64 + dy * 9 + dx;
        } else {
            src = cin - 96;
        }
    }
    float v = 0.f;
    if (src >= 0) v = W[((long)oc * 145 + src) * 9 + tap];
    dst[gid] = f2bf(v);
}

// ---------------------------------------------------------------------------
// 8. MFMA implicit-GEMM conv3x3 (SAME). Block = 256 thr = 4 waves.
//    MERGED PASSES: grid z = 2*nb; even z = pass0, odd z = pass1 (independent
//    buffers/weights selected per block). Tile = 4 rows x 32 px.
//    LDS c8-plane-major [4][6*34][8]: stage writes and frag reads are both
//    16B-aligned b128; read bank starts = 4*site mod 32 -> 2-way (free).
//    Simple 2-barrier loop; latency hidden by ~7 resident blocks/CU.
//    All pads are zero-weighted (inputs finite), so no cin masking.
// ---------------------------------------------------------------------------
template <int MT, int KC, bool LK, bool FIN>
__global__ __launch_bounds__(256) void mconv_k(
    const ushortT* __restrict__ act0, const ushortT* __restrict__ act1, int actStride,
    const ushortT* __restrict__ Wb0, const ushortT* __restrict__ Wb1,
    ushortT* __restrict__ outp0, ushortT* __restrict__ outp1, int outStride,
    const float* __restrict__ bfp, float* __restrict__ fout) {

    const int CINp = KC * 32;
    const int OCp = MT * 16;
    const int tid = threadIdx.x;
    const int lane = tid & 63;
    const int wv = tid >> 6;
    const int l15 = lane & 15;
    const int quad = lane >> 4;
    const int x0 = blockIdx.x * 32;    // 10 tiles
    const int y0 = blockIdx.y * 4;     // 48 tiles
    const int pz = blockIdx.z & 1;     // pass
    const int b = blockIdx.z >> 1;     // local batch

    const ushortT* act = pz ? act1 : act0;
    const ushortT* Wb  = pz ? Wb1  : Wb0;
    ushortT* outp      = pz ? outp1 : outp0;

    __shared__ ushortT sAct[4][6 * 34][8];   // 13056 B, c8-plane-major

    f32x4 acc[MT][2];
#pragma unroll
    for (int i = 0; i < MT; ++i)
#pragma unroll
        for (int j = 0; j < 2; ++j) acc[i][j] = (f32x4)0.f;

    const long pixBase = (long)b * HW_;

    for (int kc = 0; kc < KC; ++kc) {
        __syncthreads();
        // stage 6 rows x 34 px x 32 ch; unit = 16B (8ch) chunk
        for (int u = tid; u < 6 * 34 * 4; u += 256) {
            int c8 = u & 3;
            int site = u >> 2;
            int ky = site / 34;
            int xi = site - ky * 34;
            int gy = y0 + ky - 1;
            int gx = x0 + xi - 1;
            uint4 v = make_uint4(0, 0, 0, 0);
            if ((unsigned)gy < IMH && (unsigned)gx < IMW)
                v = *(const uint4*)(act + ((pixBase + (long)gy * IMW + gx) * actStride + kc * 32 + c8 * 8));
            *(uint4*)&sAct[c8][site][0] = v;
        }
        __syncthreads();

#pragma unroll
        for (int tap = 0; tap < 9; ++tap) {
            const int ky = tap / 3, kx = tap % 3;
            const int rowb = (wv + ky) * 34 + l15 + kx;
            FragU bf[2];
#pragma unroll
            for (int nt = 0; nt < 2; ++nt)
                bf[nt].u = *(const uint4*)&sAct[quad][rowb + nt * 16][0];
            const ushortT* wp = Wb + (((long)tap * OCp + l15) * CINp + kc * 32 + quad * 8);
#pragma unroll
            for (int mt = 0; mt < MT; ++mt) {
                FragU af;
                af.u = *(const uint4*)(wp + (long)mt * 16 * CINp);
#pragma unroll
                for (int nt = 0; nt < 2; ++nt)
                    acc[mt][nt] = __builtin_amdgcn_mfma_f32_16x16x32_bf16(af.s8, bf[nt].s8, acc[mt][nt], 0, 0, 0);
            }
        }
    }

    const int yo = y0 + wv;
    if (FIN) {
        const int chBase = pz ? 2 : 0;
        if (quad == 0) {
#pragma unroll
            for (int nt = 0; nt < 2; ++nt) {
                int px = x0 + nt * 16 + l15;
#pragma unroll
                for (int r = 0; r < 2; ++r) {
                    float v = lk(acc[0][nt][r]);
                    long o = ((long)(b * 4 + chBase + r) * IMH + yo) * IMW + px;
                    fout[o] = bfp[o] + v;
                }
            }
        }
    } else {
        const long rowBase = (pixBase + (long)yo * IMW) * outStride;
#pragma unroll
        for (int nt = 0; nt < 2; ++nt) {
            long obase = rowBase + (long)(x0 + nt * 16 + l15) * outStride;
#pragma unroll
            for (int mt = 0; mt < MT; ++mt) {
                int oc = mt * 16 + quad * 4;
                ushortT pk[4];
#pragma unroll
                for (int r = 0; r < 4; ++r) {
                    float v = acc[mt][nt][r];
                    if (LK) v = lk(v);
                    pk[r] = f2bf(v);
                }
                *(uint2*)&outp[obase + oc] = *(uint2*)pk;
            }
        }
    }
}

// ---------------------------------------------------------------------------
// launch — ws-size-adaptive batch grouping; passes merged into one z-dim
// ---------------------------------------------------------------------------
extern "C" void kernel_launch(void* const* d_in, const int* in_sizes, int n_in,
                              void* d_out, int out_size, void* d_ws, size_t ws_size,
                              hipStream_t stream) {
    const float* f0  = (const float*)d_in[0];
    const float* f1  = (const float*)d_in[1];
    const float* bfp = (const float*)d_in[2];
    const float* ftf = (const float*)d_in[3];
    const float* btf = (const float*)d_in[4];
    const float* W1  = (const float*)d_in[5];
    const float* W2  = (const float*)d_in[6];
    const float* W3  = (const float*)d_in[7];
    const float* W4  = (const float*)d_in[8];
    const float* W5  = (const float*)d_in[9];
    const float* W6  = (const float*)d_in[10];
    const float* W7  = (const float*)d_in[11];
    float* out = (float*)d_out;

    char* base = (char*)d_ws;
    size_t off = 0;
    auto alloc = [&](size_t bytes) { char* p = base + off; off += (bytes + 255) & ~(size_t)255; return p; };

    float* biflow = (float*)alloc((size_t)BB * 4 * HW_ * 4);
    ushortT* WbL1a = (ushortT*)alloc((size_t)9 * 64 * 160 * 2);
    ushortT* WbL1b = (ushortT*)alloc((size_t)9 * 64 * 160 * 2);
    ushortT* WbL2 = (ushortT*)alloc((size_t)9 * 64 * 64 * 2);
    ushortT* WbL3 = (ushortT*)alloc((size_t)9 * 64 * 64 * 2);
    ushortT* WbL4 = (ushortT*)alloc((size_t)9 * 32 * 64 * 2);
    ushortT* WbL5 = (ushortT*)alloc((size_t)9 * 32 * 32 * 2);
    ushortT* WbL6 = (ushortT*)alloc((size_t)9 * 16 * 32 * 2);
    ushortT* WbL7 = (ushortT*)alloc((size_t)9 * 16 * 32 * 2);

    // per-batch bytes/px: acc0+acc1(264) + concat(448) + bufA(128) + bufB(128) = 968
    const size_t PERB = (size_t)968 * HW_;
    size_t remain = (ws_size > off + 4096) ? (ws_size - off - 4096) : 0;
    int NB = (int)(remain / (PERB + 4096));
    if (NB < 1) NB = 1;
    if (NB > BB) NB = BB;

    float*   acc0   = (float*)alloc((size_t)NB * 33 * HW_ * 4);
    float*   acc1   = (float*)alloc((size_t)NB * 33 * HW_ * 4);
    ushortT* concat = (ushortT*)alloc((size_t)NB * HW_ * CCH * 2);
    ushortT* bufA   = (ushortT*)alloc((size_t)NB * HW_ * 64 * 2);   // aliased: NB*HW*32 fp32 NHWC
    ushortT* bufB   = (ushortT*)alloc((size_t)NB * HW_ * 64 * 2);

    // pass-1 mconv ping/pong alias the (dead-after-gather) acc regions:
    // need NB*HW*64 ushorts = NB*HW*128B <= NB*HW*132B available. 16B-aligned.
    ushortT* A1 = (ushortT*)acc0;
    ushortT* B1 = (ushortT*)acc1;

    upsample_k<<<(BB * 4 * HW_ + 255) / 256, 256, 0, stream>>>(bfp, biflow);

    wconv1_k<<<(9 * 64 * 160 + 255) / 256, 256, 0, stream>>>(W1, WbL1a, 0);
    wconv1_k<<<(9 * 64 * 160 + 255) / 256, 256, 0, stream>>>(W1, WbL1b, 1);
    wconv_k<<<(9 * 64 * 64 + 255) / 256, 256, 0, stream>>>(W2, WbL2, 64, 64, 64, 64);
    wconv_k<<<(9 * 64 * 64 + 255) / 256, 256, 0, stream>>>(W3, WbL3, 64, 64, 64, 64);
    wconv_k<<<(9 * 32 * 64 + 255) / 256, 256, 0, stream>>>(W4, WbL4, 32, 32, 64, 64);
    wconv_k<<<(9 * 32 * 32 + 255) / 256, 256, 0, stream>>>(W5, WbL5, 32, 32, 32, 32);
    wconv_k<<<(9 * 16 * 32 + 255) / 256, 256, 0, stream>>>(W6, WbL6, 16, 16, 32, 32);
    wconv_k<<<(9 * 16 * 32 + 255) / 256, 256, 0, stream>>>(W7, WbL7, 2, 16, 16, 32);

    for (int g = 0; g < BB; g += NB) {
        const int nb = (BB - g < NB) ? (BB - g) : NB;
        const int npix = nb * HW_;
        const float* f0g  = f0 + (size_t)g * FC * HW_;
        const float* f1g  = f1 + (size_t)g * FC * HW_;
        const float* ftfg = ftf + (size_t)g * FC * HW_;
        const float* btfg = btf + (size_t)g * FC * HW_;
        const float* bflg = biflow + (size_t)g * 4 * HW_;
        float* outg = out + (size_t)g * 4 * HW_;

        // zero both acc regions (contiguous) in one dispatch
        zero4_k<<<2048, 256, 0, stream>>>((uint4*)acc0, (long)NB * 66 * HW_ / 4);

        // fused transpose + outlier splat
        trout_k<<<(npix + 255) / 256, 256, 0, stream>>>(f0g, bflg, 0, acc0, (float*)bufA, nb);
        trout_k<<<(npix + 255) / 256, 256, 0, stream>>>(f1g, bflg, 2, acc1, (float*)bufB, nb);

        dim3 gg(IMW / 64, IMH / 4, nb);
        gather_k<<<gg, 256, 0, stream>>>((const float*)bufA, bflg, 0, acc0, concat, 0);
        gather_k<<<gg, 256, 0, stream>>>((const float*)bufB, bflg, 2, acc1, concat, 160);

        tconv_k<<<(npix * 8 + 255) / 256, 256, 0, stream>>>(ftfg, btfg, concat, nb);

        dim3 cgrid(IMW / 32, IMH / 8, nb);
        corr_k<<<cgrid, 256, 0, stream>>>(concat);

        // merged-pass conv chain: z = 2*nb (even=pass0, odd=pass1)
        dim3 cg(10, 48, 2 * nb);
        mconv_k<4, 5, false, false><<<cg, 256, 0, stream>>>(concat, concat + 64, CCH, WbL1a, WbL1b, bufA, A1, 64, nullptr, nullptr);
        mconv_k<4, 2, false, false><<<cg, 256, 0, stream>>>(bufA, A1, 64, WbL2, WbL2, bufB, B1, 64, nullptr, nullptr);
        mconv_k<4, 2, true,  false><<<cg, 256, 0, stream>>>(bufB, B1, 64, WbL3, WbL3, bufA, A1, 64, nullptr, nullptr);
        mconv_k<2, 2, false, false><<<cg, 256, 0, stream>>>(bufA, A1, 64, WbL4, WbL4, bufB, B1, 32, nullptr, nullptr);
        mconv_k<2, 1, false, false><<<cg, 256, 0, stream>>>(bufB, B1, 32, WbL5, WbL5, bufA, A1, 32, nullptr, nullptr);
        mconv_k<1, 1, false, false><<<cg, 256, 0, stream>>>(bufA, A1, 32, WbL6, WbL6, bufB, B1, 16, nullptr, nullptr);
        mconv_k<1, 1, true,  true ><<<cg, 256, 0, stream>>>(bufB, B1, 16, WbL7, WbL7, nullptr, nullptr, 0, bflg, outg);
    }
}

// Round 6
// 1740.185 us; speedup vs baseline: 1.2526x; 1.1612x over previous
//
#include <hip/hip_runtime.h>

// Problem constants (B=8, C=32, H=192, W=320)
#define IMH 192
#define IMW 320
#define HW_ (IMH * IMW)      // 61440
#define BB 8
#define FC 32
#define GR 8                 // gather radius: covers |disp| < 8 (~4 sigma)
#define CCH 224              // concat channels/px: [p0 feat 64][corr 96][p1 feat 64]

typedef unsigned short ushortT;
typedef __attribute__((ext_vector_type(8))) short short8;   // 8 bf16 = 4 VGPRs
typedef __attribute__((ext_vector_type(4))) float f32x4;

union FragU { uint4 u; short8 s8; };

__device__ __forceinline__ ushortT f2bf(float x) {
    union { float f; unsigned u; } v; v.f = x;
    unsigned r = v.u + 0x7FFF + ((v.u >> 16) & 1);   // RNE
    return (ushortT)(r >> 16);
}
__device__ __forceinline__ float lk(float v) { return (v >= 0.f) ? v : 0.1f * v; }

// ---------------------------------------------------------------------------
// 1. bilinear 2x upsample (half-pixel centers, edge clamp) * 2.0  [full batch]
// ---------------------------------------------------------------------------
__global__ __launch_bounds__(256) void upsample_k(const float* __restrict__ in,
                                                  float* __restrict__ out) {
    int gid = blockIdx.x * 256 + threadIdx.x;
    const int total = BB * 4 * IMH * IMW;
    if (gid >= total) return;
    int ox = gid % IMW;
    int t  = gid / IMW;
    int oy = t % IMH;
    int bc = t / IMH;
    const int Hin = IMH / 2, Win = IMW / 2;
    float sy = oy * 0.5f - 0.25f;
    float sx = ox * 0.5f - 0.25f;
    float fy = floorf(sy), fx = floorf(sx);
    float ty_ = sy - fy, tx_ = sx - fx;
    int y0 = (int)fy, x0 = (int)fx;
    int y1 = y0 + 1, x1 = x0 + 1;
    y0 = max(0, min(Hin - 1, y0)); y1 = max(0, min(Hin - 1, y1));
    x0 = max(0, min(Win - 1, x0)); x1 = max(0, min(Win - 1, x1));
    const float* p = in + (long)bc * Hin * Win;
    float v00 = p[y0 * Win + x0], v01 = p[y0 * Win + x1];
    float v10 = p[y1 * Win + x0], v11 = p[y1 * Win + x1];
    float v = (1.f - ty_) * ((1.f - tx_) * v00 + tx_ * v01) +
              ty_ * ((1.f - tx_) * v10 + tx_ * v11);
    out[gid] = 2.f * v;
}

// ---------------------------------------------------------------------------
// 2. zero-init (16B granules)
// ---------------------------------------------------------------------------
__global__ __launch_bounds__(256) void zero4_k(uint4* __restrict__ p, long n) {
    long gid = (long)blockIdx.x * 256 + threadIdx.x;
    long stride = (long)gridDim.x * 256;
    uint4 z = make_uint4(0, 0, 0, 0);
    for (long i = gid; i < n; i += stride) p[i] = z;
}

// ---------------------------------------------------------------------------
// 3. fused NCHW->NHWC transpose + outlier splat.
//    Outlier = corner-events the gather window can't see (|d| > GR), EXACT
//    complement of gather coverage, decided per corner. Rare (~4 sigma).
// ---------------------------------------------------------------------------
__global__ __launch_bounds__(256) void trout_k(const float* __restrict__ feat,
                                               const float* __restrict__ biflow,
                                               int fbase,
                                               float* __restrict__ acc,
                                               float* __restrict__ nhwc, int nb) {
    int gid = blockIdx.x * 256 + threadIdx.x;
    if (gid >= nb * HW_) return;
    int b = gid / HW_;
    int p = gid - b * HW_;
    int y = p / IMW, x = p - y * IMW;

    float f[FC];
#pragma unroll
    for (int c = 0; c < FC; ++c) f[c] = feat[((long)b * FC + c) * HW_ + p];
    float4* dst = (float4*)(nhwc + ((long)b * HW_ + p) * FC);
#pragma unroll
    for (int c4 = 0; c4 < FC / 4; ++c4)
        dst[c4] = make_float4(f[c4 * 4 + 0], f[c4 * 4 + 1],
                              f[c4 * 4 + 2], f[c4 * 4 + 3]);

    const float* fl = biflow + ((long)b * 4 + fbase) * HW_;
    float fx = x + fl[p];
    float fy = y + fl[HW_ + p];
    float x0f = floorf(fx), y0f = floorf(fy);
    int ix0 = (int)x0f, iy0 = (int)y0f;
    if (ix0 >= x - GR && ix0 + 1 <= x + GR && iy0 >= y - GR && iy0 + 1 <= y + GR)
        return;
    float wx1 = fx - x0f, wy1 = fy - y0f;
    float wx0 = 1.f - wx1, wy0 = 1.f - wy1;
    float* accb = acc + (long)b * 33 * HW_;
    const int ixs[4] = {ix0, ix0 + 1, ix0, ix0 + 1};
    const int iys[4] = {iy0, iy0, iy0 + 1, iy0 + 1};
    const float ww[4] = {wx0 * wy0, wx1 * wy0, wx0 * wy1, wx1 * wy1};
#pragma unroll
    for (int k = 0; k < 4; ++k) {
        int ix = ixs[k], iy = iys[k];
        float w = ww[k];
        if (ix < 0 || ix >= IMW || iy < 0 || iy >= IMH || w == 0.f) continue;
        int dx = ix - x, dy = iy - y;
        if (dx >= -GR && dx <= GR && dy >= -GR && dy <= GR) continue;
        int q = iy * IMW + ix;
#pragma unroll
        for (int c = 0; c < FC; ++c) atomicAdd(&accb[c * HW_ + q], f[c] * w);
        atomicAdd(&accb[32 * HW_ + q], w);
    }
}

// ---------------------------------------------------------------------------
// 3c. gather splat + normalize (fused), BOTH sides in one dispatch
//     (z = 2*nb: even = side0, odd = side1). One thread per OUTPUT pixel.
//     Emits normalized warped features as bf16 directly into the concat
//     section (chOff = 0 / 160), stride CCH.
// ---------------------------------------------------------------------------
__global__ __launch_bounds__(256) void gather_k(const float* __restrict__ tf0,
                                                const float* __restrict__ tf1,
                                                const float* __restrict__ biflow,
                                                const float* __restrict__ accA,
                                                const float* __restrict__ accB,
                                                ushortT* __restrict__ concat) {
    const int side = blockIdx.z & 1;
    const int b = blockIdx.z >> 1;
    const float* tfeat = side ? tf1 : tf0;
    const float* acc   = side ? accB : accA;
    const int fbase = side ? 2 : 0;
    const int chOff = side ? 160 : 0;

    const int xBase = blockIdx.x * 64;
    const int yBase = blockIdx.y * 4;
    __shared__ float2 sF[20][80];   // 12.8 KB

    const float* fl = biflow + ((long)b * 4 + fbase) * HW_;
    for (int u = threadIdx.x; u < 20 * 80; u += 256) {
        int wy = u / 80, wx = u - wy * 80;
        int gy = yBase - GR + wy, gx = xBase - GR + wx;
        float2 t = make_float2(-1e9f, -1e9f);   // sentinel: never matches
        if ((unsigned)gy < IMH && (unsigned)gx < IMW) {
            int p = gy * IMW + gx;
            t.x = gx + fl[p];        // MUST match trout_k's "x + fl[p]" exactly
            t.y = gy + fl[HW_ + p];
        }
        sF[wy][wx] = t;
    }

    const int lx = threadIdx.x & 63, ly = threadIdx.x >> 6;
    const int ox = xBase + lx, oy = yBase + ly;
    const int q = oy * IMW + ox;
    const float* accb = acc + (long)b * 33 * HW_;

    // init from outlier contributions (mostly zero, cheap coalesced reads)
    float s[FC];
#pragma unroll
    for (int c = 0; c < FC; ++c) s[c] = accb[(long)c * HW_ + q];
    float nsum = accb[(long)32 * HW_ + q];

    __syncthreads();

    const float* tb = tfeat + (long)b * HW_ * FC;
    const int pBase = (yBase - GR + ly) * IMW + (xBase - GR + lx);

    for (int dy = 0; dy < 2 * GR + 1; ++dy) {
#pragma unroll 1
        for (int dx = 0; dx < 2 * GR + 1; ++dx) {
            float2 t = sF[ly + dy][lx + dx];
            float x0f = floorf(t.x), y0f = floorf(t.y);
            int dxm = ox - (int)x0f;
            int dym = oy - (int)y0f;
            if (((unsigned)dxm <= 1u) && ((unsigned)dym <= 1u)) {
                float wx1 = t.x - x0f, wy1 = t.y - y0f;
                float w = (dxm ? wx1 : 1.f - wx1) * (dym ? wy1 : 1.f - wy1);
                if (w != 0.f) {
                    nsum += w;
                    int pp = pBase + dy * IMW + dx;
                    const float4* fp = (const float4*)(tb + (long)pp * FC);
#pragma unroll
                    for (int c4 = 0; c4 < FC / 4; ++c4) {
                        float4 v = fp[c4];
                        s[c4 * 4 + 0] = fmaf(w, v.x, s[c4 * 4 + 0]);
                        s[c4 * 4 + 1] = fmaf(w, v.y, s[c4 * 4 + 1]);
                        s[c4 * 4 + 2] = fmaf(w, v.z, s[c4 * 4 + 2]);
                        s[c4 * 4 + 3] = fmaf(w, v.w, s[c4 * 4 + 3]);
                    }
                }
            }
        }
    }

    float inv = (nsum == 0.f) ? 1.f : (1.f / nsum);
    unsigned pk[16];
#pragma unroll
    for (int k = 0; k < 16; ++k) {
        unsigned lo = f2bf(s[2 * k] * inv);
        unsigned hi = f2bf(s[2 * k + 1] * inv);
        pk[k] = lo | (hi << 16);
    }
    uint4* dst = (uint4*)(concat + ((long)b * HW_ + q) * CCH + chOff);
    dst[0] = *(uint4*)&pk[0];
    dst[1] = *(uint4*)&pk[4];
    dst[2] = *(uint4*)&pk[8];
    dst[3] = *(uint4*)&pk[12];
}

// ---------------------------------------------------------------------------
// 4. temporal features fp32 NCHW -> bf16 into concat ch32..63 (ftf) and
//    ch192..223 (btf)
// ---------------------------------------------------------------------------
__global__ __launch_bounds__(256) void tconv_k(const float* __restrict__ ftf,
                                               const float* __restrict__ btf,
                                               ushortT* __restrict__ concat, int nb) {
    int gid = blockIdx.x * 256 + threadIdx.x;
    if (gid >= nb * HW_ * 8) return;
    int c8 = gid & 7;
    int t = gid >> 3;
    int p = t % HW_;
    int b = t / HW_;
    int ch = c8 * 8;                 // 0..63
    const float* src = (ch < 32) ? ftf + ((long)b * 32 + ch) * HW_ + p
                                 : btf + ((long)b * 32 + (ch - 32)) * HW_ + p;
    int chp = (ch < 32) ? (32 + ch) : (192 + (ch - 32));
    ushortT pk[8];
#pragma unroll
    for (int j = 0; j < 8; ++j) pk[j] = f2bf(src[(long)j * HW_]);
    *(uint4*)&concat[((long)b * HW_ + p) * CCH + chp] = *(uint4*)pk;
}

// ---------------------------------------------------------------------------
// 5. correlation volume (9x9, mean over 32 ch) + leaky -> concat ch64..159.
//    LDS-tiled from concat's p1-feat section. Tile 32x8 px; window 40x16 px.
//    Slot layout 64 + dy*10 + dx (dx=9 and ch154..159 zeroed).
// ---------------------------------------------------------------------------
__global__ __launch_bounds__(256) void corr_k(ushortT* __restrict__ concat) {
    const int b = blockIdx.z;
    const int xB = blockIdx.x * 32;
    const int yB = blockIdx.y * 8;
    __shared__ char sW[16 * 40 * 72];   // 46080 B

    const long pixBase = (long)b * HW_;

    for (int u = threadIdx.x; u < 16 * 40 * 8; u += 256) {
        int qq = u & 7;
        int site = u >> 3;
        int row = site / 40, col = site - row * 40;
        int gy = yB - 4 + row, gx = xB - 4 + col;
        uint2 v = make_uint2(0u, 0u);
        if ((unsigned)gy < IMH && (unsigned)gx < IMW)
            v = *(const uint2*)(concat + (pixBase + (long)gy * IMW + gx) * CCH + 160 + qq * 4);
        *(uint2*)(sW + site * 72 + qq * 8) = v;
    }

    const int lx = threadIdx.x & 31, ly = threadIdx.x >> 5;
    const int ox = xB + lx, oy = yB + ly;

    unsigned wr[16];
    {
        const uint4* wp = (const uint4*)(concat + (pixBase + (long)oy * IMW + ox) * CCH);
        *(uint4*)&wr[0]  = wp[0];
        *(uint4*)&wr[4]  = wp[1];
        *(uint4*)&wr[8]  = wp[2];
        *(uint4*)&wr[12] = wp[3];
    }
    float w0f[32];
#pragma unroll
    for (int k = 0; k < 16; ++k) {
        union { unsigned u; float f; } lo, hi;
        lo.u = wr[k] << 16;
        hi.u = wr[k] & 0xffff0000u;
        w0f[2 * k]     = lo.f;
        w0f[2 * k + 1] = hi.f;
    }

    __syncthreads();

    const char* lbase = sW + (ly * 40 + lx) * 72;
    unsigned* ob = (unsigned*)concat + (pixBase + (long)oy * IMW + ox) * (CCH / 2) + 32;

    for (int dy = 0; dy < 9; ++dy) {
        const char* rp = lbase + dy * (40 * 72);
        unsigned pd[5] = {0, 0, 0, 0, 0};
#pragma unroll
        for (int dx = 0; dx < 9; ++dx) {
            float s0 = 0.f, s1 = 0.f, s2 = 0.f, s3 = 0.f;
#pragma unroll
            for (int k = 0; k < 8; k += 2) {
                uint2 va = *(const uint2*)(rp + dx * 72 + k * 8);
                uint2 vb = *(const uint2*)(rp + dx * 72 + k * 8 + 8);
                union { unsigned u; float f; } c0, c1, c2, c3, d0, d1, d2, d3;
                c0.u = va.x << 16; c1.u = va.x & 0xffff0000u;
                c2.u = va.y << 16; c3.u = va.y & 0xffff0000u;
                d0.u = vb.x << 16; d1.u = vb.x & 0xffff0000u;
                d2.u = vb.y << 16; d3.u = vb.y & 0xffff0000u;
                s0 = fmaf(w0f[4 * k + 0], c0.f, s0);
                s1 = fmaf(w0f[4 * k + 1], c1.f, s1);
                s2 = fmaf(w0f[4 * k + 2], c2.f, s2);
                s3 = fmaf(w0f[4 * k + 3], c3.f, s3);
                s0 = fmaf(w0f[4 * k + 4], d0.f, s0);
                s1 = fmaf(w0f[4 * k + 5], d1.f, s1);
                s2 = fmaf(w0f[4 * k + 6], d2.f, s2);
                s3 = fmaf(w0f[4 * k + 7], d3.f, s3);
            }
            float s = ((s0 + s1) + (s2 + s3)) * (1.f / 32.f);
            s = lk(s);
            unsigned bf = f2bf(s);
            if (dx & 1) pd[dx >> 1] |= bf << 16;
            else        pd[dx >> 1] = bf;
        }
#pragma unroll
        for (int j = 0; j < 5; ++j) ob[dy * 5 + j] = pd[j];
    }
    ob[45] = 0u; ob[46] = 0u; ob[47] = 0u;   // ch154..159 zero (NaN-safe pad)
}

// ---------------------------------------------------------------------------
// 7a. weight transform (generic), kc-blocked layout:
//     dst[((kc*9 + tap)*OCp + oc)*32 + c], global cin = kc*32 + c.
// ---------------------------------------------------------------------------
__global__ __launch_bounds__(256) void wconv_k(const float* __restrict__ W,
                                               ushortT* __restrict__ dst,
                                               int OC, int OCp, int CIN, int CINp) {
    int gid = blockIdx.x * 256 + threadIdx.x;
    int total = 9 * OCp * CINp;
    if (gid >= total) return;
    int c = gid & 31;
    int t = gid >> 5;
    int oc = t % OCp;
    int t2 = t / OCp;          // kc*9 + tap
    int tap = t2 % 9;
    int kc = t2 / 9;
    int cin = kc * 32 + c;
    float v = 0.f;
    if (oc < OC && cin < CIN) v = W[((long)oc * CIN + cin) * 9 + tap];
    dst[gid] = f2bf(v);
}

// ---------------------------------------------------------------------------
// 7b. L1 weight transform, kc-blocked + concat channel permutation.
//     mode 0 (pass0, act = concat+0):  cin' 0..63 feat, 64..159 corr slots
//     mode 1 (pass1, act = concat+64): cin' 0..95 corr slots, 96..159 feat
//     corr slot s = dy*10+dx -> W cin 64+dy*9+dx (dx<9, dy<9), else zero
// ---------------------------------------------------------------------------
__global__ __launch_bounds__(256) void wconv1_k(const float* __restrict__ W,
                                                ushortT* __restrict__ dst, int mode) {
    int gid = blockIdx.x * 256 + threadIdx.x;
    const int total = 9 * 64 * 160;
    if (gid >= total) return;
    int c = gid & 31;
    int t = gid >> 5;
    int oc = t % 64;
    int t2 = t / 64;           // kc*9 + tap
    int tap = t2 % 9;
    int kc = t2 / 9;
    int cin = kc * 32 + c;     // permuted concat channel
    int src = -1;
    if (mode == 0) {
        if (cin < 64) src = cin;
        else {
            int tt = cin - 64;            // 0..95
            int dy = tt / 10, dx = tt - dy * 10;
            if (dy < 9 && dx < 9) src = 64 + dy * 9 + dx;
        }
    } else {
        if (cin < 96) {
            int dy = cin / 10, dx = cin - dy * 10;
            if (dy < 9 && dx < 9) src = 64 + dy * 9 + dx;
        } else {
            src = cin - 96;
        }
    }
    float v = 0.f;
    if (src >= 0) v = W[((long)oc * 145 + src) * 9 + tap];
    dst[gid] = f2bf(v);
}

// ---------------------------------------------------------------------------
// 8. MFMA implicit-GEMM conv3x3 (SAME). Block = 256 thr = 4 waves.
//    MERGED PASSES: grid z = 2*nb (even=pass0, odd=pass1). Tile 4 rows x 32 px.
//    Software-pipelined tap loop: tap0 weights issued BEFORE the staging
//    barrier; inside the unrolled loop, tap+1's weights (global) and
//    B-fragments (LDS) are issued before tap's MFMAs. All buffer selection
//    is compile-time (tap parity under full unroll).
//    Weights are kc-blocked: Wb[((kc*9+tap)*OCp+oc)*32+c].
// ---------------------------------------------------------------------------
template <int MT, int KC, bool LK, bool FIN>
__global__ __launch_bounds__(256) void mconv_k(
    const ushortT* __restrict__ act0, const ushortT* __restrict__ act1, int actStride,
    const ushortT* __restrict__ Wb0, const ushortT* __restrict__ Wb1,
    ushortT* __restrict__ outp0, ushortT* __restrict__ outp1, int outStride,
    const float* __restrict__ bfp, float* __restrict__ fout) {

    const int OCp = MT * 16;
    const int tid = threadIdx.x;
    const int lane = tid & 63;
    const int wv = tid >> 6;
    const int l15 = lane & 15;
    const int quad = lane >> 4;
    const int x0 = blockIdx.x * 32;    // 10 tiles
    const int y0 = blockIdx.y * 4;     // 48 tiles
    const int pz = blockIdx.z & 1;     // pass
    const int b = blockIdx.z >> 1;     // local batch

    const ushortT* act = pz ? act1 : act0;
    const ushortT* Wb  = pz ? Wb1  : Wb0;
    ushortT* outp      = pz ? outp1 : outp0;

    __shared__ ushortT sAct[4][6 * 34][8];   // 13056 B, c8-plane-major

    f32x4 acc[MT][2];
#pragma unroll
    for (int i = 0; i < MT; ++i)
#pragma unroll
        for (int j = 0; j < 2; ++j) acc[i][j] = (f32x4)0.f;

    const long pixBase = (long)b * HW_;
    const ushortT* wlane = Wb + (l15 * 32 + quad * 8);

    for (int kc = 0; kc < KC; ++kc) {
        __syncthreads();
        // stage 6 rows x 34 px x 32 ch; unit = 16B (8ch) chunk
        for (int u = tid; u < 6 * 34 * 4; u += 256) {
            int c8 = u & 3;
            int site = u >> 2;
            int ky = site / 34;
            int xi = site - ky * 34;
            int gy = y0 + ky - 1;
            int gx = x0 + xi - 1;
            uint4 v = make_uint4(0, 0, 0, 0);
            if ((unsigned)gy < IMH && (unsigned)gx < IMW)
                v = *(const uint4*)(act + ((pixBase + (long)gy * IMW + gx) * actStride + kc * 32 + c8 * 8));
            *(uint4*)&sAct[c8][site][0] = v;
        }

        // prologue: issue tap-0 weight loads before the barrier (hides drain)
        const ushortT* wk = wlane + (long)kc * 9 * OCp * 32;
        FragU w0[MT], w1[MT];
#pragma unroll
        for (int mt = 0; mt < MT; ++mt)
            w0[mt].u = *(const uint4*)(wk + mt * 16 * 32);

        __syncthreads();

        FragU b0[2], b1[2];
        {   // B-frags for tap 0 (ky=0,kx=0)
            const int rowb = wv * 34 + l15;
#pragma unroll
            for (int nt = 0; nt < 2; ++nt)
                b0[nt].u = *(const uint4*)&sAct[quad][rowb + nt * 16][0];
        }

#pragma unroll
        for (int tap = 0; tap < 9; ++tap) {
            FragU* wc = (tap & 1) ? w1 : w0;
            FragU* wn = (tap & 1) ? w0 : w1;
            FragU* bc = (tap & 1) ? b1 : b0;
            FragU* bn = (tap & 1) ? b0 : b1;
            if (tap < 8) {
                const int tap1 = tap + 1;
                const ushortT* wp = wk + tap1 * OCp * 32;
#pragma unroll
                for (int mt = 0; mt < MT; ++mt)
                    wn[mt].u = *(const uint4*)(wp + mt * 16 * 32);
                const int ky = tap1 / 3, kx = tap1 % 3;
                const int rowb = (wv + ky) * 34 + l15 + kx;
#pragma unroll
                for (int nt = 0; nt < 2; ++nt)
                    bn[nt].u = *(const uint4*)&sAct[quad][rowb + nt * 16][0];
            }
#pragma unroll
            for (int mt = 0; mt < MT; ++mt)
#pragma unroll
                for (int nt = 0; nt < 2; ++nt)
                    acc[mt][nt] = __builtin_amdgcn_mfma_f32_16x16x32_bf16(wc[mt].s8, bc[nt].s8, acc[mt][nt], 0, 0, 0);
        }
    }

    const int yo = y0 + wv;
    if (FIN) {
        const int chBase = pz ? 2 : 0;
        if (quad == 0) {
#pragma unroll
            for (int nt = 0; nt < 2; ++nt) {
                int px = x0 + nt * 16 + l15;
#pragma unroll
                for (int r = 0; r < 2; ++r) {
                    float v = lk(acc[0][nt][r]);
                    long o = ((long)(b * 4 + chBase + r) * IMH + yo) * IMW + px;
                    fout[o] = bfp[o] + v;
                }
            }
        }
    } else {
        const long rowBase = (pixBase + (long)yo * IMW) * outStride;
#pragma unroll
        for (int nt = 0; nt < 2; ++nt) {
            long obase = rowBase + (long)(x0 + nt * 16 + l15) * outStride;
#pragma unroll
            for (int mt = 0; mt < MT; ++mt) {
                int oc = mt * 16 + quad * 4;
                ushortT pk[4];
#pragma unroll
                for (int r = 0; r < 4; ++r) {
                    float v = acc[mt][nt][r];
                    if (LK) v = lk(v);
                    pk[r] = f2bf(v);
                }
                *(uint2*)&outp[obase + oc] = *(uint2*)pk;
            }
        }
    }
}

// ---------------------------------------------------------------------------
// launch — ws-size-adaptive batch grouping; passes merged into one z-dim
// ---------------------------------------------------------------------------
extern "C" void kernel_launch(void* const* d_in, const int* in_sizes, int n_in,
                              void* d_out, int out_size, void* d_ws, size_t ws_size,
                              hipStream_t stream) {
    const float* f0  = (const float*)d_in[0];
    const float* f1  = (const float*)d_in[1];
    const float* bfp = (const float*)d_in[2];
    const float* ftf = (const float*)d_in[3];
    const float* btf = (const float*)d_in[4];
    const float* W1  = (const float*)d_in[5];
    const float* W2  = (const float*)d_in[6];
    const float* W3  = (const float*)d_in[7];
    const float* W4  = (const float*)d_in[8];
    const float* W5  = (const float*)d_in[9];
    const float* W6  = (const float*)d_in[10];
    const float* W7  = (const float*)d_in[11];
    float* out = (float*)d_out;

    char* base = (char*)d_ws;
    size_t off = 0;
    auto alloc = [&](size_t bytes) { char* p = base + off; off += (bytes + 255) & ~(size_t)255; return p; };

    float* biflow = (float*)alloc((size_t)BB * 4 * HW_ * 4);
    ushortT* WbL1a = (ushortT*)alloc((size_t)9 * 64 * 160 * 2);
    ushortT* WbL1b = (ushortT*)alloc((size_t)9 * 64 * 160 * 2);
    ushortT* WbL2 = (ushortT*)alloc((size_t)9 * 64 * 64 * 2);
    ushortT* WbL3 = (ushortT*)alloc((size_t)9 * 64 * 64 * 2);
    ushortT* WbL4 = (ushortT*)alloc((size_t)9 * 32 * 64 * 2);
    ushortT* WbL5 = (ushortT*)alloc((size_t)9 * 32 * 32 * 2);
    ushortT* WbL6 = (ushortT*)alloc((size_t)9 * 16 * 32 * 2);
    ushortT* WbL7 = (ushortT*)alloc((size_t)9 * 16 * 32 * 2);

    // per-batch bytes/px: acc0+acc1(264) + concat(448) + bufA(128) + bufB(128) = 968
    const size_t PERB = (size_t)968 * HW_;
    size_t remain = (ws_size > off + 4096) ? (ws_size - off - 4096) : 0;
    int NB = (int)(remain / (PERB + 4096));
    if (NB < 1) NB = 1;
    if (NB > BB) NB = BB;

    float*   acc0   = (float*)alloc((size_t)NB * 33 * HW_ * 4);
    float*   acc1   = (float*)alloc((size_t)NB * 33 * HW_ * 4);
    ushortT* concat = (ushortT*)alloc((size_t)NB * HW_ * CCH * 2);
    ushortT* bufA   = (ushortT*)alloc((size_t)NB * HW_ * 64 * 2);   // aliased: NB*HW*32 fp32 NHWC
    ushortT* bufB   = (ushortT*)alloc((size_t)NB * HW_ * 64 * 2);

    // pass-1 mconv ping/pong alias the (dead-after-gather) acc regions
    ushortT* A1 = (ushortT*)acc0;
    ushortT* B1 = (ushortT*)acc1;

    upsample_k<<<(BB * 4 * HW_ + 255) / 256, 256, 0, stream>>>(bfp, biflow);

    wconv1_k<<<(9 * 64 * 160 + 255) / 256, 256, 0, stream>>>(W1, WbL1a, 0);
    wconv1_k<<<(9 * 64 * 160 + 255) / 256, 256, 0, stream>>>(W1, WbL1b, 1);
    wconv_k<<<(9 * 64 * 64 + 255) / 256, 256, 0, stream>>>(W2, WbL2, 64, 64, 64, 64);
    wconv_k<<<(9 * 64 * 64 + 255) / 256, 256, 0, stream>>>(W3, WbL3, 64, 64, 64, 64);
    wconv_k<<<(9 * 32 * 64 + 255) / 256, 256, 0, stream>>>(W4, WbL4, 32, 32, 64, 64);
    wconv_k<<<(9 * 32 * 32 + 255) / 256, 256, 0, stream>>>(W5, WbL5, 32, 32, 32, 32);
    wconv_k<<<(9 * 16 * 32 + 255) / 256, 256, 0, stream>>>(W6, WbL6, 16, 16, 32, 32);
    wconv_k<<<(9 * 16 * 32 + 255) / 256, 256, 0, stream>>>(W7, WbL7, 2, 16, 16, 32);

    for (int g = 0; g < BB; g += NB) {
        const int nb = (BB - g < NB) ? (BB - g) : NB;
        const int npix = nb * HW_;
        const float* f0g  = f0 + (size_t)g * FC * HW_;
        const float* f1g  = f1 + (size_t)g * FC * HW_;
        const float* ftfg = ftf + (size_t)g * FC * HW_;
        const float* btfg = btf + (size_t)g * FC * HW_;
        const float* bflg = biflow + (size_t)g * 4 * HW_;
        float* outg = out + (size_t)g * 4 * HW_;

        // zero both acc regions (contiguous) in one dispatch
        zero4_k<<<2048, 256, 0, stream>>>((uint4*)acc0, (long)NB * 66 * HW_ / 4);

        // fused transpose + outlier splat
        trout_k<<<(npix + 255) / 256, 256, 0, stream>>>(f0g, bflg, 0, acc0, (float*)bufA, nb);
        trout_k<<<(npix + 255) / 256, 256, 0, stream>>>(f1g, bflg, 2, acc1, (float*)bufB, nb);

        // merged-side gather (z = 2*nb)
        dim3 gg(IMW / 64, IMH / 4, 2 * nb);
        gather_k<<<gg, 256, 0, stream>>>((const float*)bufA, (const float*)bufB,
                                         bflg, acc0, acc1, concat);

        tconv_k<<<(npix * 8 + 255) / 256, 256, 0, stream>>>(ftfg, btfg, concat, nb);

        dim3 cgrid(IMW / 32, IMH / 8, nb);
        corr_k<<<cgrid, 256, 0, stream>>>(concat);

        // merged-pass conv chain: z = 2*nb (even=pass0, odd=pass1)
        dim3 cg(10, 48, 2 * nb);
        mconv_k<4, 5, false, false><<<cg, 256, 0, stream>>>(concat, concat + 64, CCH, WbL1a, WbL1b, bufA, A1, 64, nullptr, nullptr);
        mconv_k<4, 2, false, false><<<cg, 256, 0, stream>>>(bufA, A1, 64, WbL2, WbL2, bufB, B1, 64, nullptr, nullptr);
        mconv_k<4, 2, true,  false><<<cg, 256, 0, stream>>>(bufB, B1, 64, WbL3, WbL3, bufA, A1, 64, nullptr, nullptr);
        mconv_k<2, 2, false, false><<<cg, 256, 0, stream>>>(bufA, A1, 64, WbL4, WbL4, bufB, B1, 32, nullptr, nullptr);
        mconv_k<2, 1, false, false><<<cg, 256, 0, stream>>>(bufB, B1, 32, WbL5, WbL5, bufA, A1, 32, nullptr, nullptr);
        mconv_k<1, 1, false, false><<<cg, 256, 0, stream>>>(bufA, A1, 32, WbL6, WbL6, bufB, B1, 16, nullptr, nullptr);
        mconv_k<1, 1, true,  true ><<<cg, 256, 0, stream>>>(bufB, B1, 16, WbL7, WbL7, nullptr, nullptr, 0, bflg, outg);
    }
}

// Round 7
// 1542.565 us; speedup vs baseline: 1.4131x; 1.1281x over previous
//
#include <hip/hip_runtime.h>

// Problem constants (B=8, C=32, H=192, W=320)
#define IMH 192
#define IMW 320
#define HW_ (IMH * IMW)      // 61440
#define BB 8
#define FC 32
#define GR 8                 // gather radius: covers |disp| < 8 (~4 sigma)
#define CCH 224              // concat channels/px: [p0 feat 64][corr 96][p1 feat 64]

typedef unsigned short ushortT;
typedef __attribute__((ext_vector_type(8))) short short8;   // 8 bf16 = 4 VGPRs
typedef __attribute__((ext_vector_type(4))) float f32x4;

union FragU { uint4 u; short8 s8; };

__device__ __forceinline__ ushortT f2bf(float x) {
    union { float f; unsigned u; } v; v.f = x;
    unsigned r = v.u + 0x7FFF + ((v.u >> 16) & 1);   // RNE
    return (ushortT)(r >> 16);
}
__device__ __forceinline__ float lk(float v) { return (v >= 0.f) ? v : 0.1f * v; }

// ---------------------------------------------------------------------------
// 1. bilinear 2x upsample (half-pixel centers, edge clamp) * 2.0  [full batch]
// ---------------------------------------------------------------------------
__global__ __launch_bounds__(256) void upsample_k(const float* __restrict__ in,
                                                  float* __restrict__ out) {
    int gid = blockIdx.x * 256 + threadIdx.x;
    const int total = BB * 4 * IMH * IMW;
    if (gid >= total) return;
    int ox = gid % IMW;
    int t  = gid / IMW;
    int oy = t % IMH;
    int bc = t / IMH;
    const int Hin = IMH / 2, Win = IMW / 2;
    float sy = oy * 0.5f - 0.25f;
    float sx = ox * 0.5f - 0.25f;
    float fy = floorf(sy), fx = floorf(sx);
    float ty_ = sy - fy, tx_ = sx - fx;
    int y0 = (int)fy, x0 = (int)fx;
    int y1 = y0 + 1, x1 = x0 + 1;
    y0 = max(0, min(Hin - 1, y0)); y1 = max(0, min(Hin - 1, y1));
    x0 = max(0, min(Win - 1, x0)); x1 = max(0, min(Win - 1, x1));
    const float* p = in + (long)bc * Hin * Win;
    float v00 = p[y0 * Win + x0], v01 = p[y0 * Win + x1];
    float v10 = p[y1 * Win + x0], v11 = p[y1 * Win + x1];
    float v = (1.f - ty_) * ((1.f - tx_) * v00 + tx_ * v01) +
              ty_ * ((1.f - tx_) * v10 + tx_ * v11);
    out[gid] = 2.f * v;
}

// ---------------------------------------------------------------------------
// 2. zero-init (16B granules)
// ---------------------------------------------------------------------------
__global__ __launch_bounds__(256) void zero4_k(uint4* __restrict__ p, long n) {
    long gid = (long)blockIdx.x * 256 + threadIdx.x;
    long stride = (long)gridDim.x * 256;
    uint4 z = make_uint4(0, 0, 0, 0);
    for (long i = gid; i < n; i += stride) p[i] = z;
}

// ---------------------------------------------------------------------------
// 3. fused NCHW->NHWC transpose + outlier splat.
//    Outlier = corner-events the gather window can't see (|d| > GR), EXACT
//    complement of gather coverage, decided per corner. Rare (~4 sigma).
// ---------------------------------------------------------------------------
__global__ __launch_bounds__(256) void trout_k(const float* __restrict__ feat,
                                               const float* __restrict__ biflow,
                                               int fbase,
                                               float* __restrict__ acc,
                                               float* __restrict__ nhwc, int nb) {
    int gid = blockIdx.x * 256 + threadIdx.x;
    if (gid >= nb * HW_) return;
    int b = gid / HW_;
    int p = gid - b * HW_;
    int y = p / IMW, x = p - y * IMW;

    float f[FC];
#pragma unroll
    for (int c = 0; c < FC; ++c) f[c] = feat[((long)b * FC + c) * HW_ + p];
    float4* dst = (float4*)(nhwc + ((long)b * HW_ + p) * FC);
#pragma unroll
    for (int c4 = 0; c4 < FC / 4; ++c4)
        dst[c4] = make_float4(f[c4 * 4 + 0], f[c4 * 4 + 1],
                              f[c4 * 4 + 2], f[c4 * 4 + 3]);

    const float* fl = biflow + ((long)b * 4 + fbase) * HW_;
    float fx = x + fl[p];
    float fy = y + fl[HW_ + p];
    float x0f = floorf(fx), y0f = floorf(fy);
    int ix0 = (int)x0f, iy0 = (int)y0f;
    if (ix0 >= x - GR && ix0 + 1 <= x + GR && iy0 >= y - GR && iy0 + 1 <= y + GR)
        return;
    float wx1 = fx - x0f, wy1 = fy - y0f;
    float wx0 = 1.f - wx1, wy0 = 1.f - wy1;
    float* accb = acc + (long)b * 33 * HW_;
    const int ixs[4] = {ix0, ix0 + 1, ix0, ix0 + 1};
    const int iys[4] = {iy0, iy0, iy0 + 1, iy0 + 1};
    const float ww[4] = {wx0 * wy0, wx1 * wy0, wx0 * wy1, wx1 * wy1};
#pragma unroll
    for (int k = 0; k < 4; ++k) {
        int ix = ixs[k], iy = iys[k];
        float w = ww[k];
        if (ix < 0 || ix >= IMW || iy < 0 || iy >= IMH || w == 0.f) continue;
        int dx = ix - x, dy = iy - y;
        if (dx >= -GR && dx <= GR && dy >= -GR && dy <= GR) continue;
        int q = iy * IMW + ix;
#pragma unroll
        for (int c = 0; c < FC; ++c) atomicAdd(&accb[c * HW_ + q], f[c] * w);
        atomicAdd(&accb[32 * HW_ + q], w);
    }
}

// ---------------------------------------------------------------------------
// 3c. gather splat + normalize (fused), BOTH sides in one dispatch
//     (z = 2*nb: even = side0, odd = side1). One thread per OUTPUT pixel.
//     Emits normalized warped features as bf16 directly into the concat
//     section (chOff = 0 / 160), stride CCH.
// ---------------------------------------------------------------------------
__global__ __launch_bounds__(256) void gather_k(const float* __restrict__ tf0,
                                                const float* __restrict__ tf1,
                                                const float* __restrict__ biflow,
                                                const float* __restrict__ accA,
                                                const float* __restrict__ accB,
                                                ushortT* __restrict__ concat) {
    const int side = blockIdx.z & 1;
    const int b = blockIdx.z >> 1;
    const float* tfeat = side ? tf1 : tf0;
    const float* acc   = side ? accB : accA;
    const int fbase = side ? 2 : 0;
    const int chOff = side ? 160 : 0;

    const int xBase = blockIdx.x * 64;
    const int yBase = blockIdx.y * 4;
    __shared__ float2 sF[20][80];   // 12.8 KB

    const float* fl = biflow + ((long)b * 4 + fbase) * HW_;
    for (int u = threadIdx.x; u < 20 * 80; u += 256) {
        int wy = u / 80, wx = u - wy * 80;
        int gy = yBase - GR + wy, gx = xBase - GR + wx;
        float2 t = make_float2(-1e9f, -1e9f);   // sentinel: never matches
        if ((unsigned)gy < IMH && (unsigned)gx < IMW) {
            int p = gy * IMW + gx;
            t.x = gx + fl[p];        // MUST match trout_k's "x + fl[p]" exactly
            t.y = gy + fl[HW_ + p];
        }
        sF[wy][wx] = t;
    }

    const int lx = threadIdx.x & 63, ly = threadIdx.x >> 6;
    const int ox = xBase + lx, oy = yBase + ly;
    const int q = oy * IMW + ox;
    const float* accb = acc + (long)b * 33 * HW_;

    // init from outlier contributions (mostly zero, cheap coalesced reads)
    float s[FC];
#pragma unroll
    for (int c = 0; c < FC; ++c) s[c] = accb[(long)c * HW_ + q];
    float nsum = accb[(long)32 * HW_ + q];

    __syncthreads();

    const float* tb = tfeat + (long)b * HW_ * FC;
    const int pBase = (yBase - GR + ly) * IMW + (xBase - GR + lx);

    for (int dy = 0; dy < 2 * GR + 1; ++dy) {
#pragma unroll 1
        for (int dx = 0; dx < 2 * GR + 1; ++dx) {
            float2 t = sF[ly + dy][lx + dx];
            float x0f = floorf(t.x), y0f = floorf(t.y);
            int dxm = ox - (int)x0f;
            int dym = oy - (int)y0f;
            if (((unsigned)dxm <= 1u) && ((unsigned)dym <= 1u)) {
                float wx1 = t.x - x0f, wy1 = t.y - y0f;
                float w = (dxm ? wx1 : 1.f - wx1) * (dym ? wy1 : 1.f - wy1);
                if (w != 0.f) {
                    nsum += w;
                    int pp = pBase + dy * IMW + dx;
                    const float4* fp = (const float4*)(tb + (long)pp * FC);
#pragma unroll
                    for (int c4 = 0; c4 < FC / 4; ++c4) {
                        float4 v = fp[c4];
                        s[c4 * 4 + 0] = fmaf(w, v.x, s[c4 * 4 + 0]);
                        s[c4 * 4 + 1] = fmaf(w, v.y, s[c4 * 4 + 1]);
                        s[c4 * 4 + 2] = fmaf(w, v.z, s[c4 * 4 + 2]);
                        s[c4 * 4 + 3] = fmaf(w, v.w, s[c4 * 4 + 3]);
                    }
                }
            }
        }
    }

    float inv = (nsum == 0.f) ? 1.f : (1.f / nsum);
    unsigned pk[16];
#pragma unroll
    for (int k = 0; k < 16; ++k) {
        unsigned lo = f2bf(s[2 * k] * inv);
        unsigned hi = f2bf(s[2 * k + 1] * inv);
        pk[k] = lo | (hi << 16);
    }
    uint4* dst = (uint4*)(concat + ((long)b * HW_ + q) * CCH + chOff);
    dst[0] = *(uint4*)&pk[0];
    dst[1] = *(uint4*)&pk[4];
    dst[2] = *(uint4*)&pk[8];
    dst[3] = *(uint4*)&pk[12];
}

// ---------------------------------------------------------------------------
// 4. temporal features fp32 NCHW -> bf16 into concat ch32..63 (ftf) and
//    ch192..223 (btf)
// ---------------------------------------------------------------------------
__global__ __launch_bounds__(256) void tconv_k(const float* __restrict__ ftf,
                                               const float* __restrict__ btf,
                                               ushortT* __restrict__ concat, int nb) {
    int gid = blockIdx.x * 256 + threadIdx.x;
    if (gid >= nb * HW_ * 8) return;
    int c8 = gid & 7;
    int t = gid >> 3;
    int p = t % HW_;
    int b = t / HW_;
    int ch = c8 * 8;                 // 0..63
    const float* src = (ch < 32) ? ftf + ((long)b * 32 + ch) * HW_ + p
                                 : btf + ((long)b * 32 + (ch - 32)) * HW_ + p;
    int chp = (ch < 32) ? (32 + ch) : (192 + (ch - 32));
    ushortT pk[8];
#pragma unroll
    for (int j = 0; j < 8; ++j) pk[j] = f2bf(src[(long)j * HW_]);
    *(uint4*)&concat[((long)b * HW_ + p) * CCH + chp] = *(uint4*)pk;
}

// ---------------------------------------------------------------------------
// 5. correlation volume (9x9, mean over 32 ch) + leaky -> concat ch64..159.
//    LDS-tiled from concat's p1-feat section. Tile 32x8 px; window 40x16 px.
//    Slot layout 64 + dy*10 + dx (dx=9 and ch154..159 zeroed).
// ---------------------------------------------------------------------------
__global__ __launch_bounds__(256) void corr_k(ushortT* __restrict__ concat) {
    const int b = blockIdx.z;
    const int xB = blockIdx.x * 32;
    const int yB = blockIdx.y * 8;
    __shared__ char sW[16 * 40 * 72];   // 46080 B

    const long pixBase = (long)b * HW_;

    for (int u = threadIdx.x; u < 16 * 40 * 8; u += 256) {
        int qq = u & 7;
        int site = u >> 3;
        int row = site / 40, col = site - row * 40;
        int gy = yB - 4 + row, gx = xB - 4 + col;
        uint2 v = make_uint2(0u, 0u);
        if ((unsigned)gy < IMH && (unsigned)gx < IMW)
            v = *(const uint2*)(concat + (pixBase + (long)gy * IMW + gx) * CCH + 160 + qq * 4);
        *(uint2*)(sW + site * 72 + qq * 8) = v;
    }

    const int lx = threadIdx.x & 31, ly = threadIdx.x >> 5;
    const int ox = xB + lx, oy = yB + ly;

    unsigned wr[16];
    {
        const uint4* wp = (const uint4*)(concat + (pixBase + (long)oy * IMW + ox) * CCH);
        *(uint4*)&wr[0]  = wp[0];
        *(uint4*)&wr[4]  = wp[1];
        *(uint4*)&wr[8]  = wp[2];
        *(uint4*)&wr[12] = wp[3];
    }
    float w0f[32];
#pragma unroll
    for (int k = 0; k < 16; ++k) {
        union { unsigned u; float f; } lo, hi;
        lo.u = wr[k] << 16;
        hi.u = wr[k] & 0xffff0000u;
        w0f[2 * k]     = lo.f;
        w0f[2 * k + 1] = hi.f;
    }

    __syncthreads();

    const char* lbase = sW + (ly * 40 + lx) * 72;
    unsigned* ob = (unsigned*)concat + (pixBase + (long)oy * IMW + ox) * (CCH / 2) + 32;

    for (int dy = 0; dy < 9; ++dy) {
        const char* rp = lbase + dy * (40 * 72);
        unsigned pd[5] = {0, 0, 0, 0, 0};
#pragma unroll
        for (int dx = 0; dx < 9; ++dx) {
            float s0 = 0.f, s1 = 0.f, s2 = 0.f, s3 = 0.f;
#pragma unroll
            for (int k = 0; k < 8; k += 2) {
                uint2 va = *(const uint2*)(rp + dx * 72 + k * 8);
                uint2 vb = *(const uint2*)(rp + dx * 72 + k * 8 + 8);
                union { unsigned u; float f; } c0, c1, c2, c3, d0, d1, d2, d3;
                c0.u = va.x << 16; c1.u = va.x & 0xffff0000u;
                c2.u = va.y << 16; c3.u = va.y & 0xffff0000u;
                d0.u = vb.x << 16; d1.u = vb.x & 0xffff0000u;
                d2.u = vb.y << 16; d3.u = vb.y & 0xffff0000u;
                s0 = fmaf(w0f[4 * k + 0], c0.f, s0);
                s1 = fmaf(w0f[4 * k + 1], c1.f, s1);
                s2 = fmaf(w0f[4 * k + 2], c2.f, s2);
                s3 = fmaf(w0f[4 * k + 3], c3.f, s3);
                s0 = fmaf(w0f[4 * k + 4], d0.f, s0);
                s1 = fmaf(w0f[4 * k + 5], d1.f, s1);
                s2 = fmaf(w0f[4 * k + 6], d2.f, s2);
                s3 = fmaf(w0f[4 * k + 7], d3.f, s3);
            }
            float s = ((s0 + s1) + (s2 + s3)) * (1.f / 32.f);
            s = lk(s);
            unsigned bf = f2bf(s);
            if (dx & 1) pd[dx >> 1] |= bf << 16;
            else        pd[dx >> 1] = bf;
        }
#pragma unroll
        for (int j = 0; j < 5; ++j) ob[dy * 5 + j] = pd[j];
    }
    ob[45] = 0u; ob[46] = 0u; ob[47] = 0u;   // ch154..159 zero (NaN-safe pad)
}

// ---------------------------------------------------------------------------
// 7a. weight transform (generic), kc-blocked layout:
//     dst[((kc*9 + tap)*OCp + oc)*32 + c], global cin = kc*32 + c.
// ---------------------------------------------------------------------------
__global__ __launch_bounds__(256) void wconv_k(const float* __restrict__ W,
                                               ushortT* __restrict__ dst,
                                               int OC, int OCp, int CIN, int CINp) {
    int gid = blockIdx.x * 256 + threadIdx.x;
    int total = 9 * OCp * CINp;
    if (gid >= total) return;
    int c = gid & 31;
    int t = gid >> 5;
    int oc = t % OCp;
    int t2 = t / OCp;          // kc*9 + tap
    int tap = t2 % 9;
    int kc = t2 / 9;
    int cin = kc * 32 + c;
    float v = 0.f;
    if (oc < OC && cin < CIN) v = W[((long)oc * CIN + cin) * 9 + tap];
    dst[gid] = f2bf(v);
}

// ---------------------------------------------------------------------------
// 7b. L1 weight transform, kc-blocked + concat channel permutation.
//     mode 0 (pass0, act = concat+0):  cin' 0..63 feat, 64..159 corr slots
//     mode 1 (pass1, act = concat+64): cin' 0..95 corr slots, 96..159 feat
//     corr slot s = dy*10+dx -> W cin 64+dy*9+dx (dx<9, dy<9), else zero
// ---------------------------------------------------------------------------
__global__ __launch_bounds__(256) void wconv1_k(const float* __restrict__ W,
                                                ushortT* __restrict__ dst, int mode) {
    int gid = blockIdx.x * 256 + threadIdx.x;
    const int total = 9 * 64 * 160;
    if (gid >= total) return;
    int c = gid & 31;
    int t = gid >> 5;
    int oc = t % 64;
    int t2 = t / 64;           // kc*9 + tap
    int tap = t2 % 9;
    int kc = t2 / 9;
    int cin = kc * 32 + c;     // permuted concat channel
    int src = -1;
    if (mode == 0) {
        if (cin < 64) src = cin;
        else {
            int tt = cin - 64;            // 0..95
            int dy = tt / 10, dx = tt - dy * 10;
            if (dy < 9 && dx < 9) src = 64 + dy * 9 + dx;
        }
    } else {
        if (cin < 96) {
            int dy = cin / 10, dx = cin - dy * 10;
            if (dy < 9 && dx < 9) src = 64 + dy * 9 + dx;
        } else {
            src = cin - 96;
        }
    }
    float v = 0.f;
    if (src >= 0) v = W[((long)oc * 145 + src) * 9 + tap];
    dst[gid] = f2bf(v);
}

// ---------------------------------------------------------------------------
// 8. MFMA implicit-GEMM conv3x3 (SAME). Block = 256 thr = 4 waves.
//    MERGED PASSES: grid z = 2*nb (even=pass0, odd=pass1).
//    Tile = 4 rows x 64 px; wave wv owns row y0+wv (4 N-tiles of 16 px),
//    MT M-tiles of 16 oc. STANDARD GEMM STRUCTURE: both weights AND act
//    staged in LDS per kc; tap loop is pure ds_read_b128 + MFMA (no global
//    latency on the critical path — the compiler's lgkmcnt scheduling of
//    LDS->MFMA is near-optimal).
//    LDS layout: c8-plane-major with +16B plane pad (quad planes land on
//    distinct bank offsets; all accesses 16B-aligned b128, ~2-way max).
// ---------------------------------------------------------------------------
template <int MT, int KC, bool LK, bool FIN>
__global__ __launch_bounds__(256) void mconv_k(
    const ushortT* __restrict__ act0, const ushortT* __restrict__ act1, int actStride,
    const ushortT* __restrict__ Wb0, const ushortT* __restrict__ Wb1,
    ushortT* __restrict__ outp0, ushortT* __restrict__ outp1, int outStride,
    const float* __restrict__ bfp, float* __restrict__ fout) {

    constexpr int OCp = MT * 16;
    constexpr int WPLANE = 9 * OCp * 8 + 8;   // ushorts per weight c8-plane (+16B pad)
    constexpr int APLANE = 6 * 66 * 8 + 8;    // ushorts per act c8-plane (+16B pad)
    const int tid = threadIdx.x;
    const int lane = tid & 63;
    const int wv = tid >> 6;
    const int l15 = lane & 15;
    const int quad = lane >> 4;
    const int x0 = blockIdx.x * 64;    // 5 tiles
    const int y0 = blockIdx.y * 4;     // 48 tiles
    const int pz = blockIdx.z & 1;     // pass
    const int b = blockIdx.z >> 1;     // local batch

    const ushortT* act = pz ? act1 : act0;
    const ushortT* Wb  = pz ? Wb1  : Wb0;
    ushortT* outp      = pz ? outp1 : outp0;

    __shared__ ushortT sA[4 * APLANE];   // 25.4 KB
    __shared__ ushortT sW[4 * WPLANE];   // MT=4: 36.9 KB

    f32x4 acc[MT][4];
#pragma unroll
    for (int i = 0; i < MT; ++i)
#pragma unroll
        for (int j = 0; j < 4; ++j) acc[i][j] = (f32x4)0.f;

    const long pixBase = (long)b * HW_;

    for (int kc = 0; kc < KC; ++kc) {
        __syncthreads();
        // stage act: 6 rows x 66 px x 32 ch (1584 16B units)
        for (int u = tid; u < 6 * 66 * 4; u += 256) {
            int c8 = u & 3;
            int site = u >> 2;
            int ky = site / 66;
            int xi = site - ky * 66;
            int gy = y0 + ky - 1;
            int gx = x0 + xi - 1;
            uint4 v = make_uint4(0, 0, 0, 0);
            if ((unsigned)gy < IMH && (unsigned)gx < IMW)
                v = *(const uint4*)(act + ((pixBase + (long)gy * IMW + gx) * actStride + kc * 32 + c8 * 8));
            *(uint4*)&sA[c8 * APLANE + site * 8] = v;
        }
        // stage weights for this kc: 9*OCp*4 16B units (L2-hot, contiguous)
        {
            const ushortT* wk = Wb + (long)kc * 9 * OCp * 32;
            for (int u = tid; u < 9 * OCp * 4; u += 256) {
                int c8 = u & 3;
                int row = u >> 2;           // tap*OCp + oc
                *(uint4*)&sW[c8 * WPLANE + row * 8] =
                    *(const uint4*)(wk + row * 32 + c8 * 8);
            }
        }
        __syncthreads();

#pragma unroll
        for (int tap = 0; tap < 9; ++tap) {
            const int ky = tap / 3, kx = tap % 3;
            FragU wf[MT];
#pragma unroll
            for (int mt = 0; mt < MT; ++mt)
                wf[mt].u = *(const uint4*)&sW[quad * WPLANE + (tap * OCp + mt * 16 + l15) * 8];
            FragU bf[4];
            const int rowb = (wv + ky) * 66 + l15 + kx;
#pragma unroll
            for (int nt = 0; nt < 4; ++nt)
                bf[nt].u = *(const uint4*)&sA[quad * APLANE + (rowb + nt * 16) * 8];
#pragma unroll
            for (int mt = 0; mt < MT; ++mt)
#pragma unroll
                for (int nt = 0; nt < 4; ++nt)
                    acc[mt][nt] = __builtin_amdgcn_mfma_f32_16x16x32_bf16(wf[mt].s8, bf[nt].s8, acc[mt][nt], 0, 0, 0);
        }
    }

    const int yo = y0 + wv;
    if (FIN) {
        const int chBase = pz ? 2 : 0;
        if (quad == 0) {
#pragma unroll
            for (int nt = 0; nt < 4; ++nt) {
                int px = x0 + nt * 16 + l15;
#pragma unroll
                for (int r = 0; r < 2; ++r) {
                    float v = lk(acc[0][nt][r]);
                    long o = ((long)(b * 4 + chBase + r) * IMH + yo) * IMW + px;
                    fout[o] = bfp[o] + v;
                }
            }
        }
    } else {
        const long rowBase = (pixBase + (long)yo * IMW) * outStride;
#pragma unroll
        for (int nt = 0; nt < 4; ++nt) {
            long obase = rowBase + (long)(x0 + nt * 16 + l15) * outStride;
#pragma unroll
            for (int mt = 0; mt < MT; ++mt) {
                int oc = mt * 16 + quad * 4;
                ushortT pk[4];
#pragma unroll
                for (int r = 0; r < 4; ++r) {
                    float v = acc[mt][nt][r];
                    if (LK) v = lk(v);
                    pk[r] = f2bf(v);
                }
                *(uint2*)&outp[obase + oc] = *(uint2*)pk;
            }
        }
    }
}

// ---------------------------------------------------------------------------
// launch — ws-size-adaptive batch grouping; passes merged into one z-dim
// ---------------------------------------------------------------------------
extern "C" void kernel_launch(void* const* d_in, const int* in_sizes, int n_in,
                              void* d_out, int out_size, void* d_ws, size_t ws_size,
                              hipStream_t stream) {
    const float* f0  = (const float*)d_in[0];
    const float* f1  = (const float*)d_in[1];
    const float* bfp = (const float*)d_in[2];
    const float* ftf = (const float*)d_in[3];
    const float* btf = (const float*)d_in[4];
    const float* W1  = (const float*)d_in[5];
    const float* W2  = (const float*)d_in[6];
    const float* W3  = (const float*)d_in[7];
    const float* W4  = (const float*)d_in[8];
    const float* W5  = (const float*)d_in[9];
    const float* W6  = (const float*)d_in[10];
    const float* W7  = (const float*)d_in[11];
    float* out = (float*)d_out;

    char* base = (char*)d_ws;
    size_t off = 0;
    auto alloc = [&](size_t bytes) { char* p = base + off; off += (bytes + 255) & ~(size_t)255; return p; };

    float* biflow = (float*)alloc((size_t)BB * 4 * HW_ * 4);
    ushortT* WbL1a = (ushortT*)alloc((size_t)9 * 64 * 160 * 2);
    ushortT* WbL1b = (ushortT*)alloc((size_t)9 * 64 * 160 * 2);
    ushortT* WbL2 = (ushortT*)alloc((size_t)9 * 64 * 64 * 2);
    ushortT* WbL3 = (ushortT*)alloc((size_t)9 * 64 * 64 * 2);
    ushortT* WbL4 = (ushortT*)alloc((size_t)9 * 32 * 64 * 2);
    ushortT* WbL5 = (ushortT*)alloc((size_t)9 * 32 * 32 * 2);
    ushortT* WbL6 = (ushortT*)alloc((size_t)9 * 16 * 32 * 2);
    ushortT* WbL7 = (ushortT*)alloc((size_t)9 * 16 * 32 * 2);

    // per-batch bytes/px: acc0+acc1(264) + concat(448) + bufA(128) + bufB(128) = 968
    const size_t PERB = (size_t)968 * HW_;
    size_t remain = (ws_size > off + 4096) ? (ws_size - off - 4096) : 0;
    int NB = (int)(remain / (PERB + 4096));
    if (NB < 1) NB = 1;
    if (NB > BB) NB = BB;

    float*   acc0   = (float*)alloc((size_t)NB * 33 * HW_ * 4);
    float*   acc1   = (float*)alloc((size_t)NB * 33 * HW_ * 4);
    ushortT* concat = (ushortT*)alloc((size_t)NB * HW_ * CCH * 2);
    ushortT* bufA   = (ushortT*)alloc((size_t)NB * HW_ * 64 * 2);   // aliased: NB*HW*32 fp32 NHWC
    ushortT* bufB   = (ushortT*)alloc((size_t)NB * HW_ * 64 * 2);

    // pass-1 mconv ping/pong alias the (dead-after-gather) acc regions
    ushortT* A1 = (ushortT*)acc0;
    ushortT* B1 = (ushortT*)acc1;

    upsample_k<<<(BB * 4 * HW_ + 255) / 256, 256, 0, stream>>>(bfp, biflow);

    wconv1_k<<<(9 * 64 * 160 + 255) / 256, 256, 0, stream>>>(W1, WbL1a, 0);
    wconv1_k<<<(9 * 64 * 160 + 255) / 256, 256, 0, stream>>>(W1, WbL1b, 1);
    wconv_k<<<(9 * 64 * 64 + 255) / 256, 256, 0, stream>>>(W2, WbL2, 64, 64, 64, 64);
    wconv_k<<<(9 * 64 * 64 + 255) / 256, 256, 0, stream>>>(W3, WbL3, 64, 64, 64, 64);
    wconv_k<<<(9 * 32 * 64 + 255) / 256, 256, 0, stream>>>(W4, WbL4, 32, 32, 64, 64);
    wconv_k<<<(9 * 32 * 32 + 255) / 256, 256, 0, stream>>>(W5, WbL5, 32, 32, 32, 32);
    wconv_k<<<(9 * 16 * 32 + 255) / 256, 256, 0, stream>>>(W6, WbL6, 16, 16, 32, 32);
    wconv_k<<<(9 * 16 * 32 + 255) / 256, 256, 0, stream>>>(W7, WbL7, 2, 16, 16, 32);

    for (int g = 0; g < BB; g += NB) {
        const int nb = (BB - g < NB) ? (BB - g) : NB;
        const int npix = nb * HW_;
        const float* f0g  = f0 + (size_t)g * FC * HW_;
        const float* f1g  = f1 + (size_t)g * FC * HW_;
        const float* ftfg = ftf + (size_t)g * FC * HW_;
        const float* btfg = btf + (size_t)g * FC * HW_;
        const float* bflg = biflow + (size_t)g * 4 * HW_;
        float* outg = out + (size_t)g * 4 * HW_;

        // zero both acc regions (contiguous) in one dispatch
        zero4_k<<<2048, 256, 0, stream>>>((uint4*)acc0, (long)NB * 66 * HW_ / 4);

        // fused transpose + outlier splat
        trout_k<<<(npix + 255) / 256, 256, 0, stream>>>(f0g, bflg, 0, acc0, (float*)bufA, nb);
        trout_k<<<(npix + 255) / 256, 256, 0, stream>>>(f1g, bflg, 2, acc1, (float*)bufB, nb);

        // merged-side gather (z = 2*nb)
        dim3 gg(IMW / 64, IMH / 4, 2 * nb);
        gather_k<<<gg, 256, 0, stream>>>((const float*)bufA, (const float*)bufB,
                                         bflg, acc0, acc1, concat);

        tconv_k<<<(npix * 8 + 255) / 256, 256, 0, stream>>>(ftfg, btfg, concat, nb);

        dim3 cgrid(IMW / 32, IMH / 8, nb);
        corr_k<<<cgrid, 256, 0, stream>>>(concat);

        // merged-pass conv chain: z = 2*nb (even=pass0, odd=pass1)
        dim3 cg(5, 48, 2 * nb);
        mconv_k<4, 5, false, false><<<cg, 256, 0, stream>>>(concat, concat + 64, CCH, WbL1a, WbL1b, bufA, A1, 64, nullptr, nullptr);
        mconv_k<4, 2, false, false><<<cg, 256, 0, stream>>>(bufA, A1, 64, WbL2, WbL2, bufB, B1, 64, nullptr, nullptr);
        mconv_k<4, 2, true,  false><<<cg, 256, 0, stream>>>(bufB, B1, 64, WbL3, WbL3, bufA, A1, 64, nullptr, nullptr);
        mconv_k<2, 2, false, false><<<cg, 256, 0, stream>>>(bufA, A1, 64, WbL4, WbL4, bufB, B1, 32, nullptr, nullptr);
        mconv_k<2, 1, false, false><<<cg, 256, 0, stream>>>(bufB, B1, 32, WbL5, WbL5, bufA, A1, 32, nullptr, nullptr);
        mconv_k<1, 1, false, false><<<cg, 256, 0, stream>>>(bufA, A1, 32, WbL6, WbL6, bufB, B1, 16, nullptr, nullptr);
        mconv_k<1, 1, true,  true ><<<cg, 256, 0, stream>>>(bufB, B1, 16, WbL7, WbL7, nullptr, nullptr, 0, bflg, outg);
    }
}